// Round 3
// baseline (302.406 us; speedup 1.0000x reference)
//
#include <hip/hip_runtime.h>
#include <cstddef>
#include <cstdint>

typedef __attribute__((ext_vector_type(8))) short short8;
typedef __attribute__((ext_vector_type(4))) float f32x4;
typedef __attribute__((ext_vector_type(16))) float f32x16;

#define GLOAD_LDS16(gp, lp) __builtin_amdgcn_global_load_lds( \
    (const __attribute__((address_space(1))) void*)(gp),      \
    (__attribute__((address_space(3))) void*)(lp), 16, 0, 0)

__device__ __forceinline__ short f2bf(float f) {
    union { float f; unsigned u; } v; v.f = f;
    unsigned r = v.u + 0x7fffu + ((v.u >> 16) & 1u);
    return (short)(r >> 16);
}

// ---------------------------------------------------------------------------
// Prep: fused x,y f32->bf16 conversion + all 5 weight transposes (f32 [R][C]
// -> bf16 [C][R]). One launch replaces 7.
// blocks 0..8191: conversion (2048 elems each). 8192..8543: transposes.
// ---------------------------------------------------------------------------
__device__ __forceinline__ void transpose_tile_f32(
    const float* __restrict__ in, short* __restrict__ out,
    int R, int C, int ty, int tx)
{
    __shared__ short tile[64][68];
    int r0 = ty * 64, c0 = tx * 64;
    int t = threadIdx.x, tr = t >> 6, tc = t & 63;
#pragma unroll
    for (int i = 0; i < 16; ++i) {
        int r = i * 4 + tr;
        tile[r][tc] = f2bf(in[(size_t)(r0 + r) * C + (c0 + tc)]);
    }
    __syncthreads();
#pragma unroll
    for (int i = 0; i < 16; ++i) {
        int r = i * 4 + tr;
        out[(size_t)(c0 + r) * R + (r0 + tc)] = tile[tc][r];
    }
}

__global__ __launch_bounds__(256) void prep_kernel(
    const float* __restrict__ x, const float* __restrict__ y,
    const float* __restrict__ Wq, const float* __restrict__ Wk,
    const float* __restrict__ Wv, const float* __restrict__ W1,
    const float* __restrict__ W2,
    short* xb, short* yb,
    short* WqT, short* WkT, short* WvT, short* W1T, short* W2T)
{
    int bid = blockIdx.x, t = threadIdx.x;
    if (bid < 8192) {
        size_t e = ((size_t)bid << 11) + (size_t)t * 8;
        const float* src; short* dst; size_t o2;
        if (e < 8388608) { src = x; dst = xb; o2 = e; }
        else             { src = y; dst = yb; o2 = e - 8388608; }
        f32x4 a = *(const f32x4*)(src + o2);
        f32x4 b = *(const f32x4*)(src + o2 + 4);
        short8 v;
        v[0] = f2bf(a[0]); v[1] = f2bf(a[1]); v[2] = f2bf(a[2]); v[3] = f2bf(a[3]);
        v[4] = f2bf(b[0]); v[5] = f2bf(b[1]); v[6] = f2bf(b[2]); v[7] = f2bf(b[3]);
        *(short8*)(dst + o2) = v;
        return;
    }
    int b2 = bid - 8192;
    const float* in; short* out; int R, C;
    if (b2 < 16)       { in = Wq; out = WqT; R = 512;  C = 128; }
    else if (b2 < 32)  { in = Wk; out = WkT; R = 512;  C = 128;  b2 -= 16; }
    else if (b2 < 96)  { in = Wv; out = WvT; R = 512;  C = 512;  b2 -= 32; }
    else if (b2 < 224) { in = W1; out = W1T; R = 512;  C = 1024; b2 -= 96; }
    else               { in = W2; out = W2T; R = 1024; C = 512;  b2 -= 224; }
    int nx = C >> 6;
    transpose_tile_f32(in, out, R, C, b2 / nx, b2 % nx);
}

// ---------------------------------------------------------------------------
// bf16 transpose (for v -> v^T per batch)
// ---------------------------------------------------------------------------
__global__ __launch_bounds__(256) void transpose_bf_kernel(
    const short* __restrict__ in, short* __restrict__ out,
    int R, int C, long long in_bstride, long long out_bstride)
{
    __shared__ short tile[64][68];
    in  += (size_t)blockIdx.z * in_bstride;
    out += (size_t)blockIdx.z * out_bstride;
    int r0 = blockIdx.y * 64, c0 = blockIdx.x * 64;
    int t = threadIdx.x, tr = t >> 6, tc = t & 63;
#pragma unroll
    for (int i = 0; i < 16; ++i) {
        int r = i * 4 + tr;
        tile[r][tc] = in[(size_t)(r0 + r) * C + (c0 + tc)];
    }
    __syncthreads();
#pragma unroll
    for (int i = 0; i < 16; ++i) {
        int r = i * 4 + tr;
        out[(size_t)(c0 + r) * R + (r0 + tc)] = tile[tc][r];
    }
}

// ---------------------------------------------------------------------------
// bf16 MFMA GEMM, m97 structure: 128x128 tile, BK=64, global_load_lds w=16
// with both-sides ch^(row&7) swizzle. Dual-input support (q/k fusion).
// EPI 0: store bf16 | EPI 2: +bias, GELU, bf16 | EPI 3: +bias, +resid, f32.
// ---------------------------------------------------------------------------
template<int EPI>
__global__ __launch_bounds__(256, 2) void gemm_kernel(
    const short* __restrict__ A0, const short* __restrict__ B0, void* out0,
    const short* __restrict__ A1, const short* __restrict__ B1, void* out1,
    int split, const float* __restrict__ bias, const float* __restrict__ resid,
    int N, int K)
{
    __shared__ short As[128][64];
    __shared__ short Bs[128][64];
    int bid = blockIdx.x;
    const short* A = A0; const short* BT = B0; void* outp = out0;
    if (bid >= split) { bid -= split; A = A1; BT = B1; outp = out1; }
    const int nb = N >> 7;
    const int m0 = (bid / nb) << 7;
    const int n0 = (bid % nb) << 7;
    const int t = threadIdx.x, l = t & 63, w = t >> 6;
    const int wm = w >> 1, wn = w & 1;
    const int lo = l & 15, hi = l >> 4;

    f32x4 acc[4][4] = {};

    const int srow = l >> 3;                 // row within 8-row segment
    const int scg  = (l & 7) ^ (srow & 7);   // inverse-swizzled source chunk

    for (int kt = 0; kt < K; kt += 64) {
#pragma unroll
        for (int i = 0; i < 4; ++i) {
            int seg = w * 4 + i;
            int row = seg * 8 + srow;
            GLOAD_LDS16(A + (size_t)(m0 + row) * K + kt + scg * 8, &As[seg * 8][0]);
        }
#pragma unroll
        for (int i = 0; i < 4; ++i) {
            int seg = w * 4 + i;
            int row = seg * 8 + srow;
            GLOAD_LDS16(BT + (size_t)(n0 + row) * K + kt + scg * 8, &Bs[seg * 8][0]);
        }
        __syncthreads();
#pragma unroll
        for (int kk = 0; kk < 2; ++kk) {
            short8 af[4], bfv[4];
            const int rc = ((kk * 4 + hi) ^ (lo & 7)) * 8;
#pragma unroll
            for (int mi = 0; mi < 4; ++mi)
                af[mi] = *(const short8*)&As[wm * 64 + mi * 16 + lo][rc];
#pragma unroll
            for (int ni = 0; ni < 4; ++ni)
                bfv[ni] = *(const short8*)&Bs[wn * 64 + ni * 16 + lo][rc];
            __builtin_amdgcn_s_setprio(1);
#pragma unroll
            for (int mi = 0; mi < 4; ++mi)
#pragma unroll
                for (int ni = 0; ni < 4; ++ni)
                    acc[mi][ni] = __builtin_amdgcn_mfma_f32_16x16x32_bf16(
                        af[mi], bfv[ni], acc[mi][ni], 0, 0, 0);
            __builtin_amdgcn_s_setprio(0);
        }
        __syncthreads();
    }

#pragma unroll
    for (int mi = 0; mi < 4; ++mi) {
#pragma unroll
        for (int ni = 0; ni < 4; ++ni) {
#pragma unroll
            for (int r = 0; r < 4; ++r) {
                int row = m0 + wm * 64 + mi * 16 + hi * 4 + r;
                int col = n0 + wn * 64 + ni * 16 + lo;
                size_t idx = (size_t)row * N + col;
                float v = acc[mi][ni][r];
                if (EPI == 0) {
                    ((short*)outp)[idx] = f2bf(v);
                } else if (EPI == 2) {
                    v += bias[col];
                    v = 0.5f * v * (1.0f + erff(v * 0.70710678118654752f));
                    ((short*)outp)[idx] = f2bf(v);
                } else {
                    v += bias[col] + resid[idx];
                    ((float*)outp)[idx] = v;
                }
            }
        }
    }
}

// ---------------------------------------------------------------------------
// Flash attention + residual. grid 512 (2 blocks/CU): bid&7 = batch (XCD
// affinity), 32 q-rows per block. 4 waves: wave qt owns 128 of 512 v-dims.
// K: LDS double-buffered via global_load_lds w=16, ch^(row&15) swizzle,
// 1 barrier/tile. V: direct global B-fragments (L2-resident, no LDS).
// Swapped QK^T (mfma(K,Q)) -> in-lane softmax; P in-register via
// v_cvt_pk_bf16_f32 + shfl_xor(32); defer-max rescale.
// ---------------------------------------------------------------------------
__global__ __launch_bounds__(256, 2) void flash_kernel(
    const float* __restrict__ x,   // [8][2048][512] f32
    const short* __restrict__ qb,  // [8*2048][128] bf16
    const short* __restrict__ kb,  // [8*2048][128] bf16
    const short* __restrict__ vT,  // [8][512][2048] bf16
    float* __restrict__ xres)      // [8][2048][512] f32
{
    __shared__ short ks[2][64][128];   // 32 KB

    const int bid = blockIdx.x;
    const int n = bid & 7;
    const int q0 = (bid >> 3) << 5;
    const int t = threadIdx.x, l = t & 63, w = t >> 6;
    const int qt = w;                       // v-dim quarter
    const int lo5 = l & 31, hi2 = l >> 5;
    const float C1 = 0.08838834764831845f * 1.4426950408889634f; // scale*log2e

    const short* kbase = kb + ((size_t)(n * 2048) << 7);
    const short* vbase = vT + ((size_t)(n * 512) << 11);

    // Q B-fragments in registers: lane holds Q[qrow=lo5][d = s*16 + hi2*8 + j]
    short8 qf[8];
    {
        const short* qrow = qb + ((size_t)(n * 2048 + q0 + lo5) << 7);
#pragma unroll
        for (int s = 0; s < 8; ++s)
            qf[s] = *(const short8*)(qrow + s * 16 + hi2 * 8);
    }

    f32x16 o[4] = {};
    float m_run = -1e30f, l_run = 0.f;

    // prologue: stage K tile 0 into buf 0
#pragma unroll
    for (int i = 0; i < 4; ++i) {
        int seg = w * 4 + i;
        int row = seg * 4 + (l >> 4);
        int cg = (l & 15) ^ (row & 15);
        GLOAD_LDS16(kbase + ((size_t)row << 7) + cg * 8, &ks[0][seg * 4][0]);
    }
    __syncthreads();

    for (int kt = 0; kt < 2048; kt += 64) {
        const int buf = (kt >> 6) & 1;
        const bool hn = (kt + 64) < 2048;
        if (hn) {   // stage next K tile into buf^1 (no wait; barrier drains)
#pragma unroll
            for (int i = 0; i < 4; ++i) {
                int seg = w * 4 + i;
                int row = seg * 4 + (l >> 4);
                int cg = (l & 15) ^ (row & 15);
                GLOAD_LDS16(kbase + ((size_t)(kt + 64 + row) << 7) + cg * 8,
                            &ks[buf ^ 1][seg * 4][0]);
            }
        }

        // V fragments for this tile: direct global (consumed in PV)
        short8 vf[16];
#pragma unroll
        for (int ks2 = 0; ks2 < 4; ++ks2)
#pragma unroll
            for (int nb2 = 0; nb2 < 4; ++nb2) {
                int row = qt * 128 + nb2 * 32 + lo5;
                vf[ks2 * 4 + nb2] = *(const short8*)
                    (vbase + ((size_t)row << 11) + kt + ks2 * 16 + hi2 * 8);
            }

        // QK^T swapped: sacc[m] = S[key][qrow=lo5]
        f32x16 sacc[2] = {};
        __builtin_amdgcn_s_setprio(1);
#pragma unroll
        for (int m = 0; m < 2; ++m) {
            int krow = m * 32 + lo5;
#pragma unroll
            for (int s = 0; s < 8; ++s) {
                short8 kf = *(const short8*)
                    &ks[buf][krow][((s * 2 + hi2) ^ (krow & 15)) * 8];
                sacc[m] = __builtin_amdgcn_mfma_f32_32x32x16_bf16(kf, qf[s], sacc[m], 0, 0, 0);
            }
        }
        __builtin_amdgcn_s_setprio(0);

        // in-lane softmax (exp2 domain)
        float mt = sacc[0][0];
#pragma unroll
        for (int r = 1; r < 16; ++r) mt = fmaxf(mt, sacc[0][r]);
#pragma unroll
        for (int r = 0; r < 16; ++r) mt = fmaxf(mt, sacc[1][r]);
        mt = fmaxf(mt, __shfl_xor(mt, 32));

        if (!__all(mt - m_run <= 90.509668f)) {   // 8 e-units of headroom
            float m_new = fmaxf(m_run, mt);
            float alpha = exp2f((m_run - m_new) * C1);
            l_run *= alpha;
#pragma unroll
            for (int r = 0; r < 16; ++r) {
                int qr = (r & 3) + 8 * (r >> 2) + 4 * hi2;
                float ar = __shfl(alpha, qr);
#pragma unroll
                for (int nb2 = 0; nb2 < 4; ++nb2) o[nb2][r] *= ar;
            }
            m_run = m_new;
        }
        const float mC1 = m_run * C1;
        float lsum = 0.f;
#pragma unroll
        for (int m = 0; m < 2; ++m)
#pragma unroll
            for (int r = 0; r < 16; ++r) {
                float p = exp2f(fmaf(sacc[m][r], C1, -mC1));
                sacc[m][r] = p;
                lsum += p;
            }
        l_run += lsum;

        // P -> bf16 A-fragments in-register (cvt_pk + shfl_xor(32))
        short8 pa[4];
#pragma unroll
        for (int m = 0; m < 2; ++m) {
            int wq[8], sx[8];
#pragma unroll
            for (int q2 = 0; q2 < 8; ++q2) {
                int a;
                asm("v_cvt_pk_bf16_f32 %0, %1, %2"
                    : "=v"(a) : "v"(sacc[m][2 * q2]), "v"(sacc[m][2 * q2 + 1]));
                wq[q2] = a;
            }
#pragma unroll
            for (int q2 = 0; q2 < 8; ++q2) sx[q2] = __shfl_xor(wq[q2], 32);
            union { int i[4]; short8 v; } u0, u1;
            u0.i[0] = hi2 ? sx[2] : wq[0];
            u0.i[1] = hi2 ? sx[3] : wq[1];
            u0.i[2] = hi2 ? wq[2] : sx[0];
            u0.i[3] = hi2 ? wq[3] : sx[1];
            u1.i[0] = hi2 ? sx[6] : wq[4];
            u1.i[1] = hi2 ? sx[7] : wq[5];
            u1.i[2] = hi2 ? wq[6] : sx[4];
            u1.i[3] = hi2 ? wq[7] : sx[5];
            pa[2 * m] = u0.v;
            pa[2 * m + 1] = u1.v;
        }

        // O += P V (V fragments already in registers)
        __builtin_amdgcn_s_setprio(1);
#pragma unroll
        for (int ks2 = 0; ks2 < 4; ++ks2)
#pragma unroll
            for (int nb2 = 0; nb2 < 4; ++nb2)
                o[nb2] = __builtin_amdgcn_mfma_f32_32x32x16_bf16(
                    pa[ks2], vf[ks2 * 4 + nb2], o[nb2], 0, 0, 0);
        __builtin_amdgcn_s_setprio(0);

        if (hn) __syncthreads();   // buf^1 staged + all reads of buf done
    }

    // epilogue: normalize + residual
    float l_tot = l_run + __shfl_xor(l_run, 32);
    float inv = 1.0f / l_tot;
#pragma unroll
    for (int r = 0; r < 16; ++r) {
        int qr = (r & 3) + 8 * (r >> 2) + 4 * hi2;
        float ir = __shfl(inv, qr);
        int row = q0 + qr;
        size_t base = ((size_t)(n * 2048 + row) << 9) + qt * 128 + lo5;
#pragma unroll
        for (int nb2 = 0; nb2 < 4; ++nb2) {
            size_t idx = base + nb2 * 32;
            xres[idx] = x[idx] + o[nb2][r] * ir;
        }
    }
}

// ---------------------------------------------------------------------------
// LayerNorm: xres f32 [16384][512] -> hb bf16. One wave per row.
// ---------------------------------------------------------------------------
__global__ __launch_bounds__(256) void ln_kernel(
    const float* __restrict__ xr, const float* __restrict__ gamma,
    const float* __restrict__ beta, short* __restrict__ hb)
{
    int row = (blockIdx.x << 2) + (threadIdx.x >> 6);
    int lane = threadIdx.x & 63;
    const float* p = xr + ((size_t)row << 9) + lane * 8;
    f32x4 a = *(const f32x4*)p;
    f32x4 b = *(const f32x4*)(p + 4);
    float s = a[0] + a[1] + a[2] + a[3] + b[0] + b[1] + b[2] + b[3];
#pragma unroll
    for (int m = 1; m < 64; m <<= 1) s += __shfl_xor(s, m);
    float mu = s * (1.0f / 512.0f);
    float q = 0.f;
#pragma unroll
    for (int j = 0; j < 4; ++j) { float d = a[j] - mu; q += d * d; }
#pragma unroll
    for (int j = 0; j < 4; ++j) { float d = b[j] - mu; q += d * d; }
#pragma unroll
    for (int m = 1; m < 64; m <<= 1) q += __shfl_xor(q, m);
    float rs = rsqrtf(q * (1.0f / 512.0f) + 1e-5f);
    f32x4 g0 = *(const f32x4*)(gamma + lane * 8);
    f32x4 g1 = *(const f32x4*)(gamma + lane * 8 + 4);
    f32x4 e0 = *(const f32x4*)(beta + lane * 8);
    f32x4 e1 = *(const f32x4*)(beta + lane * 8 + 4);
    short8 ov;
#pragma unroll
    for (int j = 0; j < 4; ++j) ov[j]     = f2bf((a[j] - mu) * rs * g0[j] + e0[j]);
#pragma unroll
    for (int j = 0; j < 4; ++j) ov[4 + j] = f2bf((b[j] - mu) * rs * g1[j] + e1[j]);
    *(short8*)(hb + ((size_t)row << 9) + lane * 8) = ov;
}

// ---------------------------------------------------------------------------
extern "C" void kernel_launch(void* const* d_in, const int* in_sizes, int n_in,
                              void* d_out, int out_size, void* d_ws, size_t ws_size,
                              hipStream_t stream)
{
    const float* x     = (const float*)d_in[0];
    const float* y     = (const float*)d_in[1];
    const float* Wq    = (const float*)d_in[2];
    const float* Wk    = (const float*)d_in[3];
    const float* Wv    = (const float*)d_in[4];
    const float* gamma = (const float*)d_in[5];
    const float* beta  = (const float*)d_in[6];
    const float* W1    = (const float*)d_in[7];
    const float* b1    = (const float*)d_in[8];
    const float* W2    = (const float*)d_in[9];
    const float* b2    = (const float*)d_in[10];
    float* out = (float*)d_out;

    char* ws = (char*)d_ws;
    size_t off = 0;
    auto alloc = [&](size_t bytes) -> void* {
        void* p = ws + off;
        off += (bytes + 255) & ~(size_t)255;
        return p;
    };
    short* WqT = (short*)alloc((size_t)128 * 512 * 2);
    short* WkT = (short*)alloc((size_t)128 * 512 * 2);
    short* WvT = (short*)alloc((size_t)512 * 512 * 2);
    short* W1T = (short*)alloc((size_t)1024 * 512 * 2);
    short* W2T = (short*)alloc((size_t)512 * 1024 * 2);
    short* qb  = (short*)alloc((size_t)16384 * 128 * 2);
    short* kbf = (short*)alloc((size_t)16384 * 128 * 2);
    // aliased regions (lifetimes are disjoint, launches are stream-ordered):
    short* xb  = (short*)alloc((size_t)16384 * 512 * 2);   // later: hb
    short* hb  = xb;
    short* yb  = (short*)alloc((size_t)16384 * 512 * 2);   // later: vT
    short* vT  = yb;
    short* gb  = (short*)alloc((size_t)16384 * 1024 * 2);  // first 16MB: vb
    short* vb  = gb;

    // 1. prep: x,y -> bf16 + all weight transposes
    prep_kernel<<<8544, 256, 0, stream>>>(x, y, Wq, Wk, Wv, W1, W2,
                                          xb, yb, WqT, WkT, WvT, W1T, W2T);
    // 2. fused q & k projections (bid<128: q=xb*Wq; else k=yb*Wk)
    gemm_kernel<0><<<256, 256, 0, stream>>>(xb, WqT, qb, yb, WkT, kbf, 128,
                                            nullptr, nullptr, 128, 512);
    // 3. v projection
    gemm_kernel<0><<<512, 256, 0, stream>>>(yb, WvT, vb, yb, WvT, vb, 1 << 30,
                                            nullptr, nullptr, 512, 512);
    // 4. v -> v^T per batch: [2048][512] -> [512][2048]
    transpose_bf_kernel<<<dim3(8, 32, 8), 256, 0, stream>>>(
        vb, vT, 2048, 512, (long long)2048 * 512, (long long)512 * 2048);
    // 5. attention + residual -> d_out (xres)
    flash_kernel<<<512, 256, 0, stream>>>(x, qb, kbf, vT, out);
    // 6. layernorm -> hb
    ln_kernel<<<4096, 256, 0, stream>>>(out, gamma, beta, hb);
    // 7. MLP
    gemm_kernel<2><<<1024, 256, 0, stream>>>(hb, W1T, gb, hb, W1T, gb, 1 << 30,
                                             b1, nullptr, 1024, 512);
    gemm_kernel<3><<<512, 256, 0, stream>>>(gb, W2T, out, gb, W2T, out, 1 << 30,
                                            b2, out, 512, 1024);

    (void)in_sizes; (void)n_in; (void)out_size; (void)ws_size;
}

// Round 4
// 224.290 us; speedup vs baseline: 1.3483x; 1.3483x over previous
//
#include <hip/hip_runtime.h>
#include <cstddef>
#include <cstdint>

typedef __attribute__((ext_vector_type(8))) short short8;
typedef __attribute__((ext_vector_type(4))) short s16x4;
typedef __attribute__((ext_vector_type(4))) float f32x4;
typedef __attribute__((ext_vector_type(16))) float f32x16;

#define GLOAD_LDS16(gp, lp) __builtin_amdgcn_global_load_lds( \
    (const __attribute__((address_space(1))) void*)(gp),      \
    (__attribute__((address_space(3))) void*)(lp), 16, 0, 0)

__device__ __forceinline__ short f2bf(float f) {
    union { float f; unsigned u; } v; v.f = f;
    unsigned r = v.u + 0x7fffu + ((v.u >> 16) & 1u);
    return (short)(r >> 16);
}

// ---------------------------------------------------------------------------
// Prep: fused x,y f32->bf16 conversion + all 5 weight transposes.
// ---------------------------------------------------------------------------
__device__ __forceinline__ void transpose_tile_f32(
    const float* __restrict__ in, short* __restrict__ out,
    int R, int C, int ty, int tx)
{
    __shared__ short tile[64][68];
    int r0 = ty * 64, c0 = tx * 64;
    int t = threadIdx.x, tr = t >> 6, tc = t & 63;
#pragma unroll
    for (int i = 0; i < 16; ++i) {
        int r = i * 4 + tr;
        tile[r][tc] = f2bf(in[(size_t)(r0 + r) * C + (c0 + tc)]);
    }
    __syncthreads();
#pragma unroll
    for (int i = 0; i < 16; ++i) {
        int r = i * 4 + tr;
        out[(size_t)(c0 + r) * R + (r0 + tc)] = tile[tc][r];
    }
}

__global__ __launch_bounds__(256) void prep_kernel(
    const float* __restrict__ x, const float* __restrict__ y,
    const float* __restrict__ Wq, const float* __restrict__ Wk,
    const float* __restrict__ Wv, const float* __restrict__ W1,
    const float* __restrict__ W2,
    short* xb, short* yb,
    short* WqT, short* WkT, short* WvT, short* W1T, short* W2T)
{
    int bid = blockIdx.x, t = threadIdx.x;
    if (bid < 8192) {
        size_t e = ((size_t)bid << 11) + (size_t)t * 8;
        const float* src; short* dst; size_t o2;
        if (e < 8388608) { src = x; dst = xb; o2 = e; }
        else             { src = y; dst = yb; o2 = e - 8388608; }
        f32x4 a = *(const f32x4*)(src + o2);
        f32x4 b = *(const f32x4*)(src + o2 + 4);
        short8 v;
        v[0] = f2bf(a[0]); v[1] = f2bf(a[1]); v[2] = f2bf(a[2]); v[3] = f2bf(a[3]);
        v[4] = f2bf(b[0]); v[5] = f2bf(b[1]); v[6] = f2bf(b[2]); v[7] = f2bf(b[3]);
        *(short8*)(dst + o2) = v;
        return;
    }
    int b2 = bid - 8192;
    const float* in; short* out; int R, C;
    if (b2 < 16)       { in = Wq; out = WqT; R = 512;  C = 128; }
    else if (b2 < 32)  { in = Wk; out = WkT; R = 512;  C = 128;  b2 -= 16; }
    else if (b2 < 96)  { in = Wv; out = WvT; R = 512;  C = 512;  b2 -= 32; }
    else if (b2 < 224) { in = W1; out = W1T; R = 512;  C = 1024; b2 -= 96; }
    else               { in = W2; out = W2T; R = 1024; C = 512;  b2 -= 224; }
    int nx = C >> 6;
    transpose_tile_f32(in, out, R, C, b2 / nx, b2 % nx);
}

// ---------------------------------------------------------------------------
// Fused q/k/v projection GEMM (m97 core: 128x128 tile, BK=64, global_load_lds
// w=16, both-sides swizzle). Epilogue writes MFMA-FRAGMENT-MAJOR bf16:
//   FRAGRC (q,k): subtile 32 rows(CDIM) x 16 cols(KDIM), lane=hi2*32+lo5
//     idx = ((row>>5)*(N>>4)+(col>>4))*512 + ((col&15)>>3)*256 + (row&31)*8 + (col&7)
//   FRAGCR (v):   subtile 16 rows(KDIM) x 32 cols(CDIM)
//     idx = ((row>>4)*(N>>5)+(col>>5))*512 + ((row&15)>>3)*256 + (col&31)*8 + (row&7)
// so flash reads every fragment as ONE coalesced 16B/lane load at base+lane*16.
// ---------------------------------------------------------------------------
__global__ __launch_bounds__(256, 2) void proj_gemm(
    const short* __restrict__ xb, const short* __restrict__ yb,
    const short* __restrict__ WqT, const short* __restrict__ WkT,
    const short* __restrict__ WvT,
    short* __restrict__ qbf, short* __restrict__ kbff, short* __restrict__ vbf)
{
    __shared__ short As[128][64];
    __shared__ short Bs[128][64];
    int bid = blockIdx.x;
    const short* A; const short* BT; short* outp; int n0, N, mode, mb;
    if (bid < 128)      { A = xb; BT = WqT; outp = qbf;  n0 = 0; N = 128; mode = 0; mb = bid; }
    else if (bid < 256) { A = yb; BT = WkT; outp = kbff; n0 = 0; N = 128; mode = 0; mb = bid - 128; }
    else { int v2 = bid - 256; A = yb; BT = WvT; outp = vbf; n0 = (v2 & 3) << 7; N = 512; mode = 1; mb = v2 >> 2; }
    const int m0 = mb << 7;
    const int K = 512;
    const int t = threadIdx.x, l = t & 63, w = t >> 6;
    const int wm = w >> 1, wn = w & 1;
    const int lo = l & 15, hi = l >> 4;

    f32x4 acc[4][4] = {};
    const int srow = l >> 3;
    const int scg  = (l & 7) ^ (srow & 7);

    for (int kt = 0; kt < K; kt += 64) {
#pragma unroll
        for (int i = 0; i < 4; ++i) {
            int seg = w * 4 + i;
            int row = seg * 8 + srow;
            GLOAD_LDS16(A + (size_t)(m0 + row) * K + kt + scg * 8, &As[seg * 8][0]);
        }
#pragma unroll
        for (int i = 0; i < 4; ++i) {
            int seg = w * 4 + i;
            int row = seg * 8 + srow;
            GLOAD_LDS16(BT + (size_t)(n0 + row) * K + kt + scg * 8, &Bs[seg * 8][0]);
        }
        __syncthreads();
#pragma unroll
        for (int kk = 0; kk < 2; ++kk) {
            short8 af[4], bfv[4];
            const int rc = ((kk * 4 + hi) ^ (lo & 7)) * 8;
#pragma unroll
            for (int mi = 0; mi < 4; ++mi)
                af[mi] = *(const short8*)&As[wm * 64 + mi * 16 + lo][rc];
#pragma unroll
            for (int ni = 0; ni < 4; ++ni)
                bfv[ni] = *(const short8*)&Bs[wn * 64 + ni * 16 + lo][rc];
            __builtin_amdgcn_s_setprio(1);
#pragma unroll
            for (int mi = 0; mi < 4; ++mi)
#pragma unroll
                for (int ni = 0; ni < 4; ++ni)
                    acc[mi][ni] = __builtin_amdgcn_mfma_f32_16x16x32_bf16(
                        af[mi], bfv[ni], acc[mi][ni], 0, 0, 0);
            __builtin_amdgcn_s_setprio(0);
        }
        __syncthreads();
    }

    if (mode == 0) {
#pragma unroll
        for (int mi = 0; mi < 4; ++mi) {
#pragma unroll
            for (int ni = 0; ni < 4; ++ni) {
                int rowb = m0 + wm * 64 + mi * 16 + hi * 4;
                int col  = n0 + wn * 64 + ni * 16 + lo;
                size_t base = ((size_t)(rowb >> 5) * (N >> 4) + (col >> 4)) * 512
                            + ((col & 15) >> 3) * 256 + (rowb & 31) * 8 + (col & 7);
#pragma unroll
                for (int r = 0; r < 4; ++r)
                    outp[base + r * 8] = f2bf(acc[mi][ni][r]);
            }
        }
    } else {
#pragma unroll
        for (int mi = 0; mi < 4; ++mi) {
#pragma unroll
            for (int ni = 0; ni < 4; ++ni) {
                int rowb = m0 + wm * 64 + mi * 16 + hi * 4;
                int col  = n0 + wn * 64 + ni * 16 + lo;
                size_t base = ((size_t)(rowb >> 4) * (N >> 5) + (col >> 5)) * 512
                            + ((rowb & 15) >> 3) * 256 + (col & 31) * 8 + (rowb & 7);
                s16x4 pk;
#pragma unroll
                for (int r = 0; r < 4; ++r) pk[r] = f2bf(acc[mi][ni][r]);
                *(s16x4*)(outp + base) = pk;
            }
        }
    }
}

// ---------------------------------------------------------------------------
// MLP GEMM (single input). EPI 2: +bias, exact GELU -> bf16 row-major.
// EPI 3: +bias +resid -> f32 row-major.
// ---------------------------------------------------------------------------
template<int EPI>
__global__ __launch_bounds__(256, 2) void gemm_kernel(
    const short* __restrict__ A, const short* __restrict__ BT, void* outv,
    const float* __restrict__ bias, const float* __restrict__ resid,
    int N, int K)
{
    __shared__ short As[128][64];
    __shared__ short Bs[128][64];
    const int nb = N >> 7;
    const int m0 = (blockIdx.x / nb) << 7;
    const int n0 = (blockIdx.x % nb) << 7;
    const int t = threadIdx.x, l = t & 63, w = t >> 6;
    const int wm = w >> 1, wn = w & 1;
    const int lo = l & 15, hi = l >> 4;

    f32x4 acc[4][4] = {};
    const int srow = l >> 3;
    const int scg  = (l & 7) ^ (srow & 7);

    for (int kt = 0; kt < K; kt += 64) {
#pragma unroll
        for (int i = 0; i < 4; ++i) {
            int seg = w * 4 + i;
            int row = seg * 8 + srow;
            GLOAD_LDS16(A + (size_t)(m0 + row) * K + kt + scg * 8, &As[seg * 8][0]);
        }
#pragma unroll
        for (int i = 0; i < 4; ++i) {
            int seg = w * 4 + i;
            int row = seg * 8 + srow;
            GLOAD_LDS16(BT + (size_t)(n0 + row) * K + kt + scg * 8, &Bs[seg * 8][0]);
        }
        __syncthreads();
#pragma unroll
        for (int kk = 0; kk < 2; ++kk) {
            short8 af[4], bfv[4];
            const int rc = ((kk * 4 + hi) ^ (lo & 7)) * 8;
#pragma unroll
            for (int mi = 0; mi < 4; ++mi)
                af[mi] = *(const short8*)&As[wm * 64 + mi * 16 + lo][rc];
#pragma unroll
            for (int ni = 0; ni < 4; ++ni)
                bfv[ni] = *(const short8*)&Bs[wn * 64 + ni * 16 + lo][rc];
            __builtin_amdgcn_s_setprio(1);
#pragma unroll
            for (int mi = 0; mi < 4; ++mi)
#pragma unroll
                for (int ni = 0; ni < 4; ++ni)
                    acc[mi][ni] = __builtin_amdgcn_mfma_f32_16x16x32_bf16(
                        af[mi], bfv[ni], acc[mi][ni], 0, 0, 0);
            __builtin_amdgcn_s_setprio(0);
        }
        __syncthreads();
    }

#pragma unroll
    for (int mi = 0; mi < 4; ++mi) {
#pragma unroll
        for (int ni = 0; ni < 4; ++ni) {
#pragma unroll
            for (int r = 0; r < 4; ++r) {
                int row = m0 + wm * 64 + mi * 16 + hi * 4 + r;
                int col = n0 + wn * 64 + ni * 16 + lo;
                size_t idx = (size_t)row * N + col;
                float v = acc[mi][ni][r];
                if (EPI == 2) {
                    v += bias[col];
                    v = 0.5f * v * (1.0f + erff(v * 0.70710678118654752f));
                    ((short*)outv)[idx] = f2bf(v);
                } else {
                    v += bias[col] + resid[idx];
                    ((float*)outv)[idx] = v;
                }
            }
        }
    }
}

// ---------------------------------------------------------------------------
// Flash attention + residual. ZERO LDS, ZERO barriers.
// grid 512: bid&7 = batch (XCD L2 affinity), 32 q-rows per block.
// 4 waves: wave qt owns v-dims [qt*128, qt*128+128). All operands are read
// as fragment-major coalesced 16B/lane loads (layout produced by proj_gemm).
// Swapped QK^T (mfma(K,Q)) -> in-lane softmax; P via cvt_pk + shfl_xor(32);
// defer-max rescale.
// ---------------------------------------------------------------------------
__global__ __launch_bounds__(256, 2) void flash_kernel(
    const float* __restrict__ x,    // [8][2048][512] f32
    const short* __restrict__ qbf,  // frag-RC layout
    const short* __restrict__ kbff, // frag-RC layout
    const short* __restrict__ vbf,  // frag-CR layout
    float* __restrict__ xres)       // [8][2048][512] f32
{
    const int bid = blockIdx.x;
    const int n = bid & 7;
    const int qtile = bid >> 3;            // 0..63
    const int q0 = qtile << 5;
    const int t = threadIdx.x, l = t & 63, qt = t >> 6;
    const int lo5 = l & 31, hi2 = l >> 5;
    const float C1 = 0.08838834764831845f * 1.4426950408889634f; // scale*log2e

    // Q fragments: one coalesced 16B load each
    short8 qf[8];
    {
        const short* qp = qbf + (((size_t)(n * 64 + qtile) * 8) << 9) + l * 8;
#pragma unroll
        for (int s = 0; s < 8; ++s)
            qf[s] = *(const short8*)(qp + (s << 9));
    }

    f32x16 o[4] = {};
    float m_run = -1e30f, l_run = 0.f;

    const short* kb0 = kbff + (((size_t)(n * 64) * 8) << 9) + l * 8;
    const short* vb0 = vbf + (((size_t)(n * 128) * 16 + qt * 4) << 9) + l * 8;

    for (int kt = 0; kt < 2048; kt += 64) {
        const short* kp = kb0 + (((size_t)(kt >> 5) * 8) << 9);
        const short* vp = vb0 + (((size_t)(kt >> 4) * 16) << 9);

        // QK^T swapped: sacc[m][r] = S[key = m*32 + crow(r,hi2)][qrow = lo5]
        f32x16 sacc[2] = {};
#pragma unroll
        for (int m = 0; m < 2; ++m) {
            short8 kf[8];
#pragma unroll
            for (int s = 0; s < 8; ++s)
                kf[s] = *(const short8*)(kp + m * 4096 + (s << 9));
            __builtin_amdgcn_s_setprio(1);
#pragma unroll
            for (int s = 0; s < 8; ++s)
                sacc[m] = __builtin_amdgcn_mfma_f32_32x32x16_bf16(kf[s], qf[s], sacc[m], 0, 0, 0);
            __builtin_amdgcn_s_setprio(0);
        }

        // issue first-half V loads (latency hidden under softmax VALU)
        short8 vfa[8];
#pragma unroll
        for (int p = 0; p < 8; ++p)
            vfa[p] = *(const short8*)(vp + (p >> 2) * 8192 + (p & 3) * 512);

        // in-lane softmax (exp2 domain)
        float mt = sacc[0][0];
#pragma unroll
        for (int r = 1; r < 16; ++r) mt = fmaxf(mt, sacc[0][r]);
#pragma unroll
        for (int r = 0; r < 16; ++r) mt = fmaxf(mt, sacc[1][r]);
        mt = fmaxf(mt, __shfl_xor(mt, 32));

        if (!__all(mt - m_run <= 90.509668f)) {
            float m_new = fmaxf(m_run, mt);
            float alpha = exp2f((m_run - m_new) * C1);
            l_run *= alpha;
#pragma unroll
            for (int r = 0; r < 16; ++r) {
                int qr = (r & 3) + 8 * (r >> 2) + 4 * hi2;
                float ar = __shfl(alpha, qr);
#pragma unroll
                for (int nb2 = 0; nb2 < 4; ++nb2) o[nb2][r] *= ar;
            }
            m_run = m_new;
        }
        const float mC1 = m_run * C1;
        float lsum = 0.f;
#pragma unroll
        for (int m = 0; m < 2; ++m)
#pragma unroll
            for (int r = 0; r < 16; ++r) {
                float p = exp2f(fmaf(sacc[m][r], C1, -mC1));
                sacc[m][r] = p;
                lsum += p;
            }
        l_run += lsum;

        // P -> bf16 A-fragments in-register
        short8 pa[4];
#pragma unroll
        for (int m = 0; m < 2; ++m) {
            int wq[8], sx[8];
#pragma unroll
            for (int q2 = 0; q2 < 8; ++q2) {
                int a;
                asm("v_cvt_pk_bf16_f32 %0, %1, %2"
                    : "=v"(a) : "v"(sacc[m][2 * q2]), "v"(sacc[m][2 * q2 + 1]));
                wq[q2] = a;
            }
#pragma unroll
            for (int q2 = 0; q2 < 8; ++q2) sx[q2] = __shfl_xor(wq[q2], 32);
            union { int i[4]; short8 v; } u0, u1;
            u0.i[0] = hi2 ? sx[2] : wq[0];
            u0.i[1] = hi2 ? sx[3] : wq[1];
            u0.i[2] = hi2 ? wq[2] : sx[0];
            u0.i[3] = hi2 ? wq[3] : sx[1];
            u1.i[0] = hi2 ? sx[6] : wq[4];
            u1.i[1] = hi2 ? sx[7] : wq[5];
            u1.i[2] = hi2 ? wq[6] : sx[4];
            u1.i[3] = hi2 ? wq[7] : sx[5];
            pa[2 * m] = u0.v;
            pa[2 * m + 1] = u1.v;
        }

        // O += P V, first half (ks2 = 0,1)
        __builtin_amdgcn_s_setprio(1);
#pragma unroll
        for (int p = 0; p < 8; ++p)
            o[p & 3] = __builtin_amdgcn_mfma_f32_32x32x16_bf16(
                pa[p >> 2], vfa[p], o[p & 3], 0, 0, 0);
        __builtin_amdgcn_s_setprio(0);

        // second half (ks2 = 2,3)
        short8 vfb[8];
#pragma unroll
        for (int p = 0; p < 8; ++p)
            vfb[p] = *(const short8*)(vp + 16384 + (p >> 2) * 8192 + (p & 3) * 512);
        __builtin_amdgcn_s_setprio(1);
#pragma unroll
        for (int p = 0; p < 8; ++p)
            o[p & 3] = __builtin_amdgcn_mfma_f32_32x32x16_bf16(
                pa[2 + (p >> 2)], vfb[p], o[p & 3], 0, 0, 0);
        __builtin_amdgcn_s_setprio(0);
    }

    // epilogue: normalize + residual
    float l_tot = l_run + __shfl_xor(l_run, 32);
    float inv = 1.0f / l_tot;
#pragma unroll
    for (int r = 0; r < 16; ++r) {
        int qr = (r & 3) + 8 * (r >> 2) + 4 * hi2;
        float ir = __shfl(inv, qr);
        int row = q0 + qr;
        size_t base = ((size_t)(n * 2048 + row) << 9) + qt * 128 + lo5;
#pragma unroll
        for (int nb2 = 0; nb2 < 4; ++nb2) {
            size_t idx = base + nb2 * 32;
            xres[idx] = x[idx] + o[nb2][r] * ir;
        }
    }
}

// ---------------------------------------------------------------------------
// LayerNorm: xres f32 [16384][512] -> hb bf16. One wave per row.
// ---------------------------------------------------------------------------
__global__ __launch_bounds__(256) void ln_kernel(
    const float* __restrict__ xr, const float* __restrict__ gamma,
    const float* __restrict__ beta, short* __restrict__ hb)
{
    int row = (blockIdx.x << 2) + (threadIdx.x >> 6);
    int lane = threadIdx.x & 63;
    const float* p = xr + ((size_t)row << 9) + lane * 8;
    f32x4 a = *(const f32x4*)p;
    f32x4 b = *(const f32x4*)(p + 4);
    float s = a[0] + a[1] + a[2] + a[3] + b[0] + b[1] + b[2] + b[3];
#pragma unroll
    for (int m = 1; m < 64; m <<= 1) s += __shfl_xor(s, m);
    float mu = s * (1.0f / 512.0f);
    float q = 0.f;
#pragma unroll
    for (int j = 0; j < 4; ++j) { float d = a[j] - mu; q += d * d; }
#pragma unroll
    for (int j = 0; j < 4; ++j) { float d = b[j] - mu; q += d * d; }
#pragma unroll
    for (int m = 1; m < 64; m <<= 1) q += __shfl_xor(q, m);
    float rs = rsqrtf(q * (1.0f / 512.0f) + 1e-5f);
    f32x4 g0 = *(const f32x4*)(gamma + lane * 8);
    f32x4 g1 = *(const f32x4*)(gamma + lane * 8 + 4);
    f32x4 e0 = *(const f32x4*)(beta + lane * 8);
    f32x4 e1 = *(const f32x4*)(beta + lane * 8 + 4);
    short8 ov;
#pragma unroll
    for (int j = 0; j < 4; ++j) ov[j]     = f2bf((a[j] - mu) * rs * g0[j] + e0[j]);
#pragma unroll
    for (int j = 0; j < 4; ++j) ov[4 + j] = f2bf((b[j] - mu) * rs * g1[j] + e1[j]);
    *(short8*)(hb + ((size_t)row << 9) + lane * 8) = ov;
}

// ---------------------------------------------------------------------------
extern "C" void kernel_launch(void* const* d_in, const int* in_sizes, int n_in,
                              void* d_out, int out_size, void* d_ws, size_t ws_size,
                              hipStream_t stream)
{
    const float* x     = (const float*)d_in[0];
    const float* y     = (const float*)d_in[1];
    const float* Wq    = (const float*)d_in[2];
    const float* Wk    = (const float*)d_in[3];
    const float* Wv    = (const float*)d_in[4];
    const float* gamma = (const float*)d_in[5];
    const float* beta  = (const float*)d_in[6];
    const float* W1    = (const float*)d_in[7];
    const float* b1    = (const float*)d_in[8];
    const float* W2    = (const float*)d_in[9];
    const float* b2    = (const float*)d_in[10];
    float* out = (float*)d_out;

    char* ws = (char*)d_ws;
    size_t off = 0;
    auto alloc = [&](size_t bytes) -> void* {
        void* p = ws + off;
        off += (bytes + 255) & ~(size_t)255;
        return p;
    };
    short* WqT  = (short*)alloc((size_t)128 * 512 * 2);
    short* WkT  = (short*)alloc((size_t)128 * 512 * 2);
    short* WvT  = (short*)alloc((size_t)512 * 512 * 2);
    short* W1T  = (short*)alloc((size_t)1024 * 512 * 2);
    short* W2T  = (short*)alloc((size_t)512 * 1024 * 2);
    short* qbf  = (short*)alloc((size_t)16384 * 128 * 2);   // frag-RC
    short* kbff = (short*)alloc((size_t)16384 * 128 * 2);   // frag-RC
    short* vbf  = (short*)alloc((size_t)16384 * 512 * 2);   // frag-CR
    short* xb   = (short*)alloc((size_t)16384 * 512 * 2);   // later: hb
    short* hb   = xb;
    short* yb   = (short*)alloc((size_t)16384 * 512 * 2);
    short* gb   = (short*)alloc((size_t)16384 * 1024 * 2);

    // 1. prep: x,y -> bf16 + weight transposes
    prep_kernel<<<8544, 256, 0, stream>>>(x, y, Wq, Wk, Wv, W1, W2,
                                          xb, yb, WqT, WkT, WvT, W1T, W2T);
    // 2. fused q/k/v projections -> fragment-major layouts
    proj_gemm<<<768, 256, 0, stream>>>(xb, yb, WqT, WkT, WvT, qbf, kbff, vbf);
    // 3. attention + residual -> d_out (xres)
    flash_kernel<<<512, 256, 0, stream>>>(x, qbf, kbff, vbf, out);
    // 4. layernorm -> hb
    ln_kernel<<<4096, 256, 0, stream>>>(out, gamma, beta, hb);
    // 5. MLP
    gemm_kernel<2><<<1024, 256, 0, stream>>>(hb, W1T, gb, b1, nullptr, 1024, 512);
    gemm_kernel<3><<<512,  256, 0, stream>>>(gb, W2T, out, b2, out, 512, 1024);

    (void)in_sizes; (void)n_in; (void)out_size; (void)ws_size;
}

// Round 5
// 179.565 us; speedup vs baseline: 1.6841x; 1.2491x over previous
//
#include <hip/hip_runtime.h>
#include <cstddef>
#include <cstdint>

typedef __attribute__((ext_vector_type(8))) short short8;
typedef __attribute__((ext_vector_type(4))) short s16x4;
typedef __attribute__((ext_vector_type(4))) float f32x4;
typedef __attribute__((ext_vector_type(16))) float f32x16;

#define GLOAD_LDS16(gp, lp) __builtin_amdgcn_global_load_lds( \
    (const __attribute__((address_space(1))) void*)(gp),      \
    (__attribute__((address_space(3))) void*)(lp), 16, 0, 0)

__device__ __forceinline__ short f2bf(float f) {
    union { float f; unsigned u; } v; v.f = f;
    unsigned r = v.u + 0x7fffu + ((v.u >> 16) & 1u);
    return (short)(r >> 16);
}

// ---------------------------------------------------------------------------
// Prep: fused x,y f32->bf16 conversion + all 5 weight transposes.
// ---------------------------------------------------------------------------
__device__ __forceinline__ void transpose_tile_f32(
    const float* __restrict__ in, short* __restrict__ out,
    int R, int C, int ty, int tx)
{
    __shared__ short tile[64][68];
    int r0 = ty * 64, c0 = tx * 64;
    int t = threadIdx.x, tr = t >> 6, tc = t & 63;
#pragma unroll
    for (int i = 0; i < 16; ++i) {
        int r = i * 4 + tr;
        tile[r][tc] = f2bf(in[(size_t)(r0 + r) * C + (c0 + tc)]);
    }
    __syncthreads();
#pragma unroll
    for (int i = 0; i < 16; ++i) {
        int r = i * 4 + tr;
        out[(size_t)(c0 + r) * R + (r0 + tc)] = tile[tc][r];
    }
}

__global__ __launch_bounds__(256) void prep_kernel(
    const float* __restrict__ x, const float* __restrict__ y,
    const float* __restrict__ Wq, const float* __restrict__ Wk,
    const float* __restrict__ Wv, const float* __restrict__ W1,
    const float* __restrict__ W2,
    short* xb, short* yb,
    short* WqT, short* WkT, short* WvT, short* W1T, short* W2T)
{
    int bid = blockIdx.x, t = threadIdx.x;
    if (bid < 8192) {
        size_t e = ((size_t)bid << 11) + (size_t)t * 8;
        const float* src; short* dst; size_t o2;
        if (e < 8388608) { src = x; dst = xb; o2 = e; }
        else             { src = y; dst = yb; o2 = e - 8388608; }
        f32x4 a = *(const f32x4*)(src + o2);
        f32x4 b = *(const f32x4*)(src + o2 + 4);
        short8 v;
        v[0] = f2bf(a[0]); v[1] = f2bf(a[1]); v[2] = f2bf(a[2]); v[3] = f2bf(a[3]);
        v[4] = f2bf(b[0]); v[5] = f2bf(b[1]); v[6] = f2bf(b[2]); v[7] = f2bf(b[3]);
        *(short8*)(dst + o2) = v;
        return;
    }
    int b2 = bid - 8192;
    const float* in; short* out; int R, C;
    if (b2 < 16)       { in = Wq; out = WqT; R = 512;  C = 128; }
    else if (b2 < 32)  { in = Wk; out = WkT; R = 512;  C = 128;  b2 -= 16; }
    else if (b2 < 96)  { in = Wv; out = WvT; R = 512;  C = 512;  b2 -= 32; }
    else if (b2 < 224) { in = W1; out = W1T; R = 512;  C = 1024; b2 -= 96; }
    else               { in = W2; out = W2T; R = 1024; C = 512;  b2 -= 224; }
    int nx = C >> 6;
    transpose_tile_f32(in, out, R, C, b2 / nx, b2 % nx);
}

// ---------------------------------------------------------------------------
// Fused q/k/v projection GEMM -> MFMA-fragment-major outputs (see r4 notes).
// ---------------------------------------------------------------------------
__global__ __launch_bounds__(256, 2) void proj_gemm(
    const short* __restrict__ xb, const short* __restrict__ yb,
    const short* __restrict__ WqT, const short* __restrict__ WkT,
    const short* __restrict__ WvT,
    short* __restrict__ qbf, short* __restrict__ kbff, short* __restrict__ vbf)
{
    __shared__ short As[128][64];
    __shared__ short Bs[128][64];
    int bid = blockIdx.x;
    const short* A; const short* BT; short* outp; int n0, N, mode, mb;
    if (bid < 128)      { A = xb; BT = WqT; outp = qbf;  n0 = 0; N = 128; mode = 0; mb = bid; }
    else if (bid < 256) { A = yb; BT = WkT; outp = kbff; n0 = 0; N = 128; mode = 0; mb = bid - 128; }
    else { int v2 = bid - 256; A = yb; BT = WvT; outp = vbf; n0 = (v2 & 3) << 7; N = 512; mode = 1; mb = v2 >> 2; }
    const int m0 = mb << 7;
    const int K = 512;
    const int t = threadIdx.x, l = t & 63, w = t >> 6;
    const int wm = w >> 1, wn = w & 1;
    const int lo = l & 15, hi = l >> 4;

    f32x4 acc[4][4] = {};
    const int srow = l >> 3;
    const int scg  = (l & 7) ^ (srow & 7);

    for (int kt = 0; kt < K; kt += 64) {
#pragma unroll
        for (int i = 0; i < 4; ++i) {
            int seg = w * 4 + i;
            int row = seg * 8 + srow;
            GLOAD_LDS16(A + (size_t)(m0 + row) * K + kt + scg * 8, &As[seg * 8][0]);
        }
#pragma unroll
        for (int i = 0; i < 4; ++i) {
            int seg = w * 4 + i;
            int row = seg * 8 + srow;
            GLOAD_LDS16(BT + (size_t)(n0 + row) * K + kt + scg * 8, &Bs[seg * 8][0]);
        }
        __syncthreads();
#pragma unroll
        for (int kk = 0; kk < 2; ++kk) {
            short8 af[4], bfv[4];
            const int rc = ((kk * 4 + hi) ^ (lo & 7)) * 8;
#pragma unroll
            for (int mi = 0; mi < 4; ++mi)
                af[mi] = *(const short8*)&As[wm * 64 + mi * 16 + lo][rc];
#pragma unroll
            for (int ni = 0; ni < 4; ++ni)
                bfv[ni] = *(const short8*)&Bs[wn * 64 + ni * 16 + lo][rc];
            __builtin_amdgcn_s_setprio(1);
#pragma unroll
            for (int mi = 0; mi < 4; ++mi)
#pragma unroll
                for (int ni = 0; ni < 4; ++ni)
                    acc[mi][ni] = __builtin_amdgcn_mfma_f32_16x16x32_bf16(
                        af[mi], bfv[ni], acc[mi][ni], 0, 0, 0);
            __builtin_amdgcn_s_setprio(0);
        }
        __syncthreads();
    }

    if (mode == 0) {
#pragma unroll
        for (int mi = 0; mi < 4; ++mi) {
#pragma unroll
            for (int ni = 0; ni < 4; ++ni) {
                int rowb = m0 + wm * 64 + mi * 16 + hi * 4;
                int col  = n0 + wn * 64 + ni * 16 + lo;
                size_t base = ((size_t)(rowb >> 5) * (N >> 4) + (col >> 4)) * 512
                            + ((col & 15) >> 3) * 256 + (rowb & 31) * 8 + (col & 7);
#pragma unroll
                for (int r = 0; r < 4; ++r)
                    outp[base + r * 8] = f2bf(acc[mi][ni][r]);
            }
        }
    } else {
#pragma unroll
        for (int mi = 0; mi < 4; ++mi) {
#pragma unroll
            for (int ni = 0; ni < 4; ++ni) {
                int rowb = m0 + wm * 64 + mi * 16 + hi * 4;
                int col  = n0 + wn * 64 + ni * 16 + lo;
                size_t base = ((size_t)(rowb >> 4) * (N >> 5) + (col >> 5)) * 512
                            + ((rowb & 15) >> 3) * 256 + (col & 31) * 8 + (rowb & 7);
                s16x4 pk;
#pragma unroll
                for (int r = 0; r < 4; ++r) pk[r] = f2bf(acc[mi][ni][r]);
                *(s16x4*)(outp + base) = pk;
            }
        }
    }
}

// ---------------------------------------------------------------------------
// MLP GEMM with XCD-aware swizzle (m-contiguous per XCD -> A panel L2-hot).
// EPI 2: +bias, exact GELU -> bf16. EPI 3: +bias +resid -> f32.
// ---------------------------------------------------------------------------
template<int EPI>
__global__ __launch_bounds__(256, 2) void gemm_kernel(
    const short* __restrict__ A, const short* __restrict__ BT, void* outv,
    const float* __restrict__ bias, const float* __restrict__ resid,
    int N, int K)
{
    __shared__ short As[128][64];
    __shared__ short Bs[128][64];
    int bid = blockIdx.x;
    const int cpx = gridDim.x >> 3;
    bid = (bid & 7) * cpx + (bid >> 3);     // XCD swizzle (grid % 8 == 0)
    const int nb = N >> 7;
    const int m0 = (bid / nb) << 7;
    const int n0 = (bid % nb) << 7;
    const int t = threadIdx.x, l = t & 63, w = t >> 6;
    const int wm = w >> 1, wn = w & 1;
    const int lo = l & 15, hi = l >> 4;

    f32x4 acc[4][4] = {};
    const int srow = l >> 3;
    const int scg  = (l & 7) ^ (srow & 7);

    for (int kt = 0; kt < K; kt += 64) {
#pragma unroll
        for (int i = 0; i < 4; ++i) {
            int seg = w * 4 + i;
            int row = seg * 8 + srow;
            GLOAD_LDS16(A + (size_t)(m0 + row) * K + kt + scg * 8, &As[seg * 8][0]);
        }
#pragma unroll
        for (int i = 0; i < 4; ++i) {
            int seg = w * 4 + i;
            int row = seg * 8 + srow;
            GLOAD_LDS16(BT + (size_t)(n0 + row) * K + kt + scg * 8, &Bs[seg * 8][0]);
        }
        __syncthreads();
#pragma unroll
        for (int kk = 0; kk < 2; ++kk) {
            short8 af[4], bfv[4];
            const int rc = ((kk * 4 + hi) ^ (lo & 7)) * 8;
#pragma unroll
            for (int mi = 0; mi < 4; ++mi)
                af[mi] = *(const short8*)&As[wm * 64 + mi * 16 + lo][rc];
#pragma unroll
            for (int ni = 0; ni < 4; ++ni)
                bfv[ni] = *(const short8*)&Bs[wn * 64 + ni * 16 + lo][rc];
            __builtin_amdgcn_s_setprio(1);
#pragma unroll
            for (int mi = 0; mi < 4; ++mi)
#pragma unroll
                for (int ni = 0; ni < 4; ++ni)
                    acc[mi][ni] = __builtin_amdgcn_mfma_f32_16x16x32_bf16(
                        af[mi], bfv[ni], acc[mi][ni], 0, 0, 0);
            __builtin_amdgcn_s_setprio(0);
        }
        __syncthreads();
    }

#pragma unroll
    for (int mi = 0; mi < 4; ++mi) {
#pragma unroll
        for (int ni = 0; ni < 4; ++ni) {
#pragma unroll
            for (int r = 0; r < 4; ++r) {
                int row = m0 + wm * 64 + mi * 16 + hi * 4 + r;
                int col = n0 + wn * 64 + ni * 16 + lo;
                size_t idx = (size_t)row * N + col;
                float v = acc[mi][ni][r];
                if (EPI == 2) {
                    v += bias[col];
                    v = 0.5f * v * (1.0f + erff(v * 0.70710678118654752f));
                    ((short*)outv)[idx] = f2bf(v);
                } else {
                    v += bias[col] + resid[idx];
                    ((float*)outv)[idx] = v;
                }
            }
        }
    }
}

// ---------------------------------------------------------------------------
// Flash attention + residual. Phase-split waves, ZERO duplication.
// grid 256 (1 blk/CU), 512 threads (8 waves), 64 q-rows/block, KVBLK=128.
// QK phase: wave (qh=w>>2, kq=w&3) computes S slice [32k x 32q] (no dup) and
// its softmax slice; running max merged via LDS mpart each tile (defer-max).
// P (bf16 A-frags) shared via LDS (16KB, conflict-free frag-major).
// PV phase: wave w owns vd-slice [w*64, w*64+64) for BOTH q-halves (V x1).
// All global operands are frag-major coalesced 16B/lane loads.
// ---------------------------------------------------------------------------
__global__ __launch_bounds__(512, 2) void flash_kernel(
    const float* __restrict__ x,    // [8][2048][512] f32
    const short* __restrict__ qbf,  // frag-RC
    const short* __restrict__ kbff, // frag-RC
    const short* __restrict__ vbf,  // frag-CR
    float* __restrict__ xres)       // [8][2048][512] f32
{
    __shared__ short Ps[2][8][512];      // [qh][key16-blk][lane*8] = 16 KB
    __shared__ float mpart[8][32];
    __shared__ float lpart[8][32];

    const int bid = blockIdx.x;
    const int n = bid & 7;
    const int qtile = bid >> 3;          // 0..31 (64 q-rows each)
    const int q0 = qtile << 6;
    const int t = threadIdx.x, l = t & 63, w = t >> 6;
    const int qh = w >> 2, kq = w & 3;
    const int lo5 = l & 31, hi2 = l >> 5;
    const float C1 = 0.08838834764831845f * 1.4426950408889634f; // scale*log2e
    const float THR = 90.509668f;        // 8 nat-log units, pre-scale domain

    // Q B-fragments for my q-half (32 q-rows)
    short8 qf[8];
    {
        const short* qp = qbf + (((size_t)(n * 64 + qtile * 2 + qh) * 8) << 9) + l * 8;
#pragma unroll
        for (int s = 0; s < 8; ++s) qf[s] = *(const short8*)(qp + (s << 9));
    }

    f32x16 o00 = {}, o01 = {}, o10 = {}, o11 = {};  // [qhalf][vd32-blk]
    float m0 = -1e30f, m1 = -1e30f, lp = 0.f;

    const short* kb0 = kbff + (((size_t)(n * 64) * 8) << 9);
    const short* vb0 = vbf + ((((size_t)(n * 128)) * 16 + w * 2) << 9);

    for (int kt = 0; kt < 2048; kt += 128) {
        // ---- QK phase: my 32-key slice ----
        const short* kp = kb0 + (((size_t)((kt >> 5) + kq) * 8) << 9) + l * 8;
        short8 kf[8];
#pragma unroll
        for (int s = 0; s < 8; ++s) kf[s] = *(const short8*)(kp + (s << 9));

        f32x16 sacc = {};
        __builtin_amdgcn_s_setprio(1);
#pragma unroll
        for (int s = 0; s < 8; ++s)
            sacc = __builtin_amdgcn_mfma_f32_32x32x16_bf16(kf[s], qf[s], sacc, 0, 0, 0);
        __builtin_amdgcn_s_setprio(0);

        // V fragments for my vd-slice (consumed in PV; latency hides here)
        short8 vf[16];
        {
            const short* vp = vb0 + (((size_t)(kt >> 4) * 16) << 9) + l * 8;
#pragma unroll
            for (int ks = 0; ks < 8; ++ks)
#pragma unroll
                for (int nb = 0; nb < 2; ++nb)
                    vf[ks * 2 + nb] = *(const short8*)(vp + (((size_t)(ks * 16 + nb)) << 9));
        }

        // ---- softmax slice + cross-wave max merge ----
        float lmax = sacc[0];
#pragma unroll
        for (int r = 1; r < 16; ++r) lmax = fmaxf(lmax, sacc[r]);
        lmax = fmaxf(lmax, __shfl_xor(lmax, 32));
        if (l < 32) mpart[w][l] = lmax;
        __syncthreads();

        float nm0 = fmaxf(fmaxf(mpart[0][lo5], mpart[1][lo5]),
                          fmaxf(mpart[2][lo5], mpart[3][lo5]));
        float nm1 = fmaxf(fmaxf(mpart[4][lo5], mpart[5][lo5]),
                          fmaxf(mpart[6][lo5], mpart[7][lo5]));
        float t0 = (nm0 > m0 + THR) ? nm0 : m0;
        float t1 = (nm1 > m1 + THR) ? nm1 : m1;
        float a0 = exp2f((m0 - t0) * C1);   // 1.0f on the common (defer) path
        float a1 = exp2f((m1 - t1) * C1);
        m0 = t0; m1 = t1;

        const float mC1 = (qh ? m1 : m0) * C1;
        float lsum = 0.f;
#pragma unroll
        for (int r = 0; r < 16; ++r) {
            float p = exp2f(fmaf(sacc[r], C1, -mC1));
            sacc[r] = p; lsum += p;
        }
        lp = lp * (qh ? a1 : a0) + lsum;

        // ---- pack P -> bf16 A-frags, share via LDS ----
        {
            int wq[8], sx[8];
#pragma unroll
            for (int q2 = 0; q2 < 8; ++q2) {
                int a;
                asm("v_cvt_pk_bf16_f32 %0, %1, %2"
                    : "=v"(a) : "v"(sacc[2 * q2]), "v"(sacc[2 * q2 + 1]));
                wq[q2] = a;
            }
#pragma unroll
            for (int q2 = 0; q2 < 8; ++q2) sx[q2] = __shfl_xor(wq[q2], 32);
            union { int i[4]; short8 v; } u0, u1;
            u0.i[0] = hi2 ? sx[2] : wq[0];
            u0.i[1] = hi2 ? sx[3] : wq[1];
            u0.i[2] = hi2 ? wq[2] : sx[0];
            u0.i[3] = hi2 ? wq[3] : sx[1];
            u1.i[0] = hi2 ? sx[6] : wq[4];
            u1.i[1] = hi2 ? sx[7] : wq[5];
            u1.i[2] = hi2 ? wq[6] : sx[4];
            u1.i[3] = hi2 ? wq[7] : sx[5];
            *(short8*)&Ps[qh][kq * 2][l * 8]     = u0.v;
            *(short8*)&Ps[qh][kq * 2 + 1][l * 8] = u1.v;
        }
        __syncthreads();

        // ---- PV phase: my vd-slice, both q-halves ----
        if (!(__all(a0 == 1.f) & __all(a1 == 1.f))) {
#pragma unroll
            for (int r = 0; r < 16; ++r) {
                int qr = (r & 3) + 8 * (r >> 2) + 4 * hi2;
                float ar0 = __shfl(a0, qr);
                float ar1 = __shfl(a1, qr);
                o00[r] *= ar0; o01[r] *= ar0;
                o10[r] *= ar1; o11[r] *= ar1;
            }
        }
        __builtin_amdgcn_s_setprio(1);
#pragma unroll
        for (int ks = 0; ks < 8; ++ks) {
            short8 p0 = *(const short8*)&Ps[0][ks][l * 8];
            short8 p1 = *(const short8*)&Ps[1][ks][l * 8];
            o00 = __builtin_amdgcn_mfma_f32_32x32x16_bf16(p0, vf[ks * 2 + 0], o00, 0, 0, 0);
            o01 = __builtin_amdgcn_mfma_f32_32x32x16_bf16(p0, vf[ks * 2 + 1], o01, 0, 0, 0);
            o10 = __builtin_amdgcn_mfma_f32_32x32x16_bf16(p1, vf[ks * 2 + 0], o10, 0, 0, 0);
            o11 = __builtin_amdgcn_mfma_f32_32x32x16_bf16(p1, vf[ks * 2 + 1], o11, 0, 0, 0);
        }
        __builtin_amdgcn_s_setprio(0);
    }

    // ---- epilogue: merge l, normalize, residual ----
    float l2 = lp + __shfl_xor(lp, 32);
    if (l < 32) lpart[w][l] = l2;
    __syncthreads();
    float li0 = 1.f / (lpart[0][lo5] + lpart[1][lo5] + lpart[2][lo5] + lpart[3][lo5]);
    float li1 = 1.f / (lpart[4][lo5] + lpart[5][lo5] + lpart[6][lo5] + lpart[7][lo5]);
#pragma unroll
    for (int r = 0; r < 16; ++r) {
        int qr = (r & 3) + 8 * (r >> 2) + 4 * hi2;
        float ir0 = __shfl(li0, qr);
        float ir1 = __shfl(li1, qr);
        int row0 = q0 + qr, row1 = q0 + 32 + qr;
        size_t b0 = ((size_t)(n * 2048 + row0) << 9) + w * 64 + lo5;
        size_t b1 = ((size_t)(n * 2048 + row1) << 9) + w * 64 + lo5;
        xres[b0]      = x[b0]      + o00[r] * ir0;
        xres[b0 + 32] = x[b0 + 32] + o01[r] * ir0;
        xres[b1]      = x[b1]      + o10[r] * ir1;
        xres[b1 + 32] = x[b1 + 32] + o11[r] * ir1;
    }
}

// ---------------------------------------------------------------------------
// LayerNorm: xres f32 [16384][512] -> hb bf16. One wave per row.
// ---------------------------------------------------------------------------
__global__ __launch_bounds__(256) void ln_kernel(
    const float* __restrict__ xr, const float* __restrict__ gamma,
    const float* __restrict__ beta, short* __restrict__ hb)
{
    int row = (blockIdx.x << 2) + (threadIdx.x >> 6);
    int lane = threadIdx.x & 63;
    const float* p = xr + ((size_t)row << 9) + lane * 8;
    f32x4 a = *(const f32x4*)p;
    f32x4 b = *(const f32x4*)(p + 4);
    float s = a[0] + a[1] + a[2] + a[3] + b[0] + b[1] + b[2] + b[3];
#pragma unroll
    for (int m = 1; m < 64; m <<= 1) s += __shfl_xor(s, m);
    float mu = s * (1.0f / 512.0f);
    float q = 0.f;
#pragma unroll
    for (int j = 0; j < 4; ++j) { float d = a[j] - mu; q += d * d; }
#pragma unroll
    for (int j = 0; j < 4; ++j) { float d = b[j] - mu; q += d * d; }
#pragma unroll
    for (int m = 1; m < 64; m <<= 1) q += __shfl_xor(q, m);
    float rs = rsqrtf(q * (1.0f / 512.0f) + 1e-5f);
    f32x4 g0 = *(const f32x4*)(gamma + lane * 8);
    f32x4 g1 = *(const f32x4*)(gamma + lane * 8 + 4);
    f32x4 e0 = *(const f32x4*)(beta + lane * 8);
    f32x4 e1 = *(const f32x4*)(beta + lane * 8 + 4);
    short8 ov;
#pragma unroll
    for (int j = 0; j < 4; ++j) ov[j]     = f2bf((a[j] - mu) * rs * g0[j] + e0[j]);
#pragma unroll
    for (int j = 0; j < 4; ++j) ov[4 + j] = f2bf((b[j] - mu) * rs * g1[j] + e1[j]);
    *(short8*)(hb + ((size_t)row << 9) + lane * 8) = ov;
}

// ---------------------------------------------------------------------------
extern "C" void kernel_launch(void* const* d_in, const int* in_sizes, int n_in,
                              void* d_out, int out_size, void* d_ws, size_t ws_size,
                              hipStream_t stream)
{
    const float* x     = (const float*)d_in[0];
    const float* y     = (const float*)d_in[1];
    const float* Wq    = (const float*)d_in[2];
    const float* Wk    = (const float*)d_in[3];
    const float* Wv    = (const float*)d_in[4];
    const float* gamma = (const float*)d_in[5];
    const float* beta  = (const float*)d_in[6];
    const float* W1    = (const float*)d_in[7];
    const float* b1    = (const float*)d_in[8];
    const float* W2    = (const float*)d_in[9];
    const float* b2    = (const float*)d_in[10];
    float* out = (float*)d_out;

    char* ws = (char*)d_ws;
    size_t off = 0;
    auto alloc = [&](size_t bytes) -> void* {
        void* p = ws + off;
        off += (bytes + 255) & ~(size_t)255;
        return p;
    };
    short* WqT  = (short*)alloc((size_t)128 * 512 * 2);
    short* WkT  = (short*)alloc((size_t)128 * 512 * 2);
    short* WvT  = (short*)alloc((size_t)512 * 512 * 2);
    short* W1T  = (short*)alloc((size_t)1024 * 512 * 2);
    short* W2T  = (short*)alloc((size_t)512 * 1024 * 2);
    short* qbf  = (short*)alloc((size_t)16384 * 128 * 2);   // frag-RC
    short* kbff = (short*)alloc((size_t)16384 * 128 * 2);   // frag-RC
    short* vbf  = (short*)alloc((size_t)16384 * 512 * 2);   // frag-CR
    short* xb   = (short*)alloc((size_t)16384 * 512 * 2);   // later: hb
    short* hb   = xb;
    short* yb   = (short*)alloc((size_t)16384 * 512 * 2);
    short* gb   = (short*)alloc((size_t)16384 * 1024 * 2);

    // 1. prep: x,y -> bf16 + weight transposes
    prep_kernel<<<8544, 256, 0, stream>>>(x, y, Wq, Wk, Wv, W1, W2,
                                          xb, yb, WqT, WkT, WvT, W1T, W2T);
    // 2. fused q/k/v projections -> fragment-major layouts
    proj_gemm<<<768, 256, 0, stream>>>(xb, yb, WqT, WkT, WvT, qbf, kbff, vbf);
    // 3. attention + residual -> d_out (xres)
    flash_kernel<<<256, 512, 0, stream>>>(x, qbf, kbff, vbf, out);
    // 4. layernorm -> hb
    ln_kernel<<<4096, 256, 0, stream>>>(out, gamma, beta, hb);
    // 5. MLP
    gemm_kernel<2><<<1024, 256, 0, stream>>>(hb, W1T, gb, b1, nullptr, 1024, 512);
    gemm_kernel<3><<<512,  256, 0, stream>>>(gb, W2T, out, b2, out, 512, 1024);

    (void)in_sizes; (void)n_in; (void)out_size; (void)ws_size;
}

// Round 7
// 172.089 us; speedup vs baseline: 1.7573x; 1.0434x over previous
//
#include <hip/hip_runtime.h>
#include <cstddef>
#include <cstdint>

typedef __attribute__((ext_vector_type(8))) short short8;
typedef __attribute__((ext_vector_type(4))) short s16x4;
typedef __attribute__((ext_vector_type(4))) float f32x4;
typedef __attribute__((ext_vector_type(16))) float f32x16;

#define GLOAD_LDS16(gp, lp) __builtin_amdgcn_global_load_lds( \
    (const __attribute__((address_space(1))) void*)(gp),      \
    (__attribute__((address_space(3))) void*)(lp), 16, 0, 0)

__device__ __forceinline__ short f2bf(float f) {
    union { float f; unsigned u; } v; v.f = f;
    unsigned r = v.u + 0x7fffu + ((v.u >> 16) & 1u);
    return (short)(r >> 16);
}

// ---------------------------------------------------------------------------
// Prep: fused x,y f32->bf16 conversion + all 5 weight transposes.
// ---------------------------------------------------------------------------
__device__ __forceinline__ void transpose_tile_f32(
    const float* __restrict__ in, short* __restrict__ out,
    int R, int C, int ty, int tx)
{
    __shared__ short tile[64][68];
    int r0 = ty * 64, c0 = tx * 64;
    int t = threadIdx.x, tr = t >> 6, tc = t & 63;
#pragma unroll
    for (int i = 0; i < 16; ++i) {
        int r = i * 4 + tr;
        tile[r][tc] = f2bf(in[(size_t)(r0 + r) * C + (c0 + tc)]);
    }
    __syncthreads();
#pragma unroll
    for (int i = 0; i < 16; ++i) {
        int r = i * 4 + tr;
        out[(size_t)(c0 + r) * R + (r0 + tc)] = tile[tc][r];
    }
}

__global__ __launch_bounds__(256) void prep_kernel(
    const float* __restrict__ x, const float* __restrict__ y,
    const float* __restrict__ Wq, const float* __restrict__ Wk,
    const float* __restrict__ Wv, const float* __restrict__ W1,
    const float* __restrict__ W2,
    short* xb, short* yb,
    short* WqT, short* WkT, short* WvT, short* W1T, short* W2T)
{
    int bid = blockIdx.x, t = threadIdx.x;
    if (bid < 8192) {
        size_t e = ((size_t)bid << 11) + (size_t)t * 8;
        const float* src; short* dst; size_t o2;
        if (e < 8388608) { src = x; dst = xb; o2 = e; }
        else             { src = y; dst = yb; o2 = e - 8388608; }
        f32x4 a = *(const f32x4*)(src + o2);
        f32x4 b = *(const f32x4*)(src + o2 + 4);
        short8 v;
        v[0] = f2bf(a[0]); v[1] = f2bf(a[1]); v[2] = f2bf(a[2]); v[3] = f2bf(a[3]);
        v[4] = f2bf(b[0]); v[5] = f2bf(b[1]); v[6] = f2bf(b[2]); v[7] = f2bf(b[3]);
        *(short8*)(dst + o2) = v;
        return;
    }
    int b2 = bid - 8192;
    const float* in; short* out; int R, C;
    if (b2 < 16)       { in = Wq; out = WqT; R = 512;  C = 128; }
    else if (b2 < 32)  { in = Wk; out = WkT; R = 512;  C = 128;  b2 -= 16; }
    else if (b2 < 96)  { in = Wv; out = WvT; R = 512;  C = 512;  b2 -= 32; }
    else if (b2 < 224) { in = W1; out = W1T; R = 512;  C = 1024; b2 -= 96; }
    else               { in = W2; out = W2T; R = 1024; C = 512;  b2 -= 224; }
    int nx = C >> 6;
    transpose_tile_f32(in, out, R, C, b2 / nx, b2 % nx);
}

// ---------------------------------------------------------------------------
// Fused q/k/v projection GEMM -> MFMA-fragment-major outputs.
//   FRAGRC (q,k): idx = ((row>>5)*(N>>4)+(col>>4))*512 + ((col&15)>>3)*256
//                       + (row&31)*8 + (col&7)
//   FRAGCR (v):   idx = ((row>>4)*(N>>5)+(col>>5))*512 + ((row&15)>>3)*256
//                       + (col&31)*8 + (row&7)
// ---------------------------------------------------------------------------
__global__ __launch_bounds__(256, 2) void proj_gemm(
    const short* __restrict__ xb, const short* __restrict__ yb,
    const short* __restrict__ WqT, const short* __restrict__ WkT,
    const short* __restrict__ WvT,
    short* __restrict__ qbf, short* __restrict__ kbff, short* __restrict__ vbf)
{
    __shared__ short As[128][64];
    __shared__ short Bs[128][64];
    int bid = blockIdx.x;
    const short* A; const short* BT; short* outp; int n0, N, mode, mb;
    if (bid < 128)      { A = xb; BT = WqT; outp = qbf;  n0 = 0; N = 128; mode = 0; mb = bid; }
    else if (bid < 256) { A = yb; BT = WkT; outp = kbff; n0 = 0; N = 128; mode = 0; mb = bid - 128; }
    else { int v2 = bid - 256; A = yb; BT = WvT; outp = vbf; n0 = (v2 & 3) << 7; N = 512; mode = 1; mb = v2 >> 2; }
    const int m0 = mb << 7;
    const int K = 512;
    const int t = threadIdx.x, l = t & 63, w = t >> 6;
    const int wm = w >> 1, wn = w & 1;
    const int lo = l & 15, hi = l >> 4;

    f32x4 acc[4][4] = {};
    const int srow = l >> 3;
    const int scg  = (l & 7) ^ (srow & 7);

    for (int kt = 0; kt < K; kt += 64) {
#pragma unroll
        for (int i = 0; i < 4; ++i) {
            int seg = w * 4 + i;
            int row = seg * 8 + srow;
            GLOAD_LDS16(A + (size_t)(m0 + row) * K + kt + scg * 8, &As[seg * 8][0]);
        }
#pragma unroll
        for (int i = 0; i < 4; ++i) {
            int seg = w * 4 + i;
            int row = seg * 8 + srow;
            GLOAD_LDS16(BT + (size_t)(n0 + row) * K + kt + scg * 8, &Bs[seg * 8][0]);
        }
        __syncthreads();
#pragma unroll
        for (int kk = 0; kk < 2; ++kk) {
            short8 af[4], bfv[4];
            const int rc = ((kk * 4 + hi) ^ (lo & 7)) * 8;
#pragma unroll
            for (int mi = 0; mi < 4; ++mi)
                af[mi] = *(const short8*)&As[wm * 64 + mi * 16 + lo][rc];
#pragma unroll
            for (int ni = 0; ni < 4; ++ni)
                bfv[ni] = *(const short8*)&Bs[wn * 64 + ni * 16 + lo][rc];
            __builtin_amdgcn_s_setprio(1);
#pragma unroll
            for (int mi = 0; mi < 4; ++mi)
#pragma unroll
                for (int ni = 0; ni < 4; ++ni)
                    acc[mi][ni] = __builtin_amdgcn_mfma_f32_16x16x32_bf16(
                        af[mi], bfv[ni], acc[mi][ni], 0, 0, 0);
            __builtin_amdgcn_s_setprio(0);
        }
        __syncthreads();
    }

    if (mode == 0) {
#pragma unroll
        for (int mi = 0; mi < 4; ++mi) {
#pragma unroll
            for (int ni = 0; ni < 4; ++ni) {
                int rowb = m0 + wm * 64 + mi * 16 + hi * 4;
                int col  = n0 + wn * 64 + ni * 16 + lo;
                size_t base = ((size_t)(rowb >> 5) * (N >> 4) + (col >> 4)) * 512
                            + ((col & 15) >> 3) * 256 + (rowb & 31) * 8 + (col & 7);
#pragma unroll
                for (int r = 0; r < 4; ++r)
                    outp[base + r * 8] = f2bf(acc[mi][ni][r]);
            }
        }
    } else {
#pragma unroll
        for (int mi = 0; mi < 4; ++mi) {
#pragma unroll
            for (int ni = 0; ni < 4; ++ni) {
                int rowb = m0 + wm * 64 + mi * 16 + hi * 4;
                int col  = n0 + wn * 64 + ni * 16 + lo;
                size_t base = ((size_t)(rowb >> 4) * (N >> 5) + (col >> 5)) * 512
                            + ((rowb & 15) >> 3) * 256 + (col & 31) * 8 + (rowb & 7);
                s16x4 pk;
#pragma unroll
                for (int r = 0; r < 4; ++r) pk[r] = f2bf(acc[mi][ni][r]);
                *(s16x4*)(outp + base) = pk;
            }
        }
    }
}

// ---------------------------------------------------------------------------
// MLP GEMM with XCD-aware swizzle.
// EPI 2: +bias, exact GELU -> bf16. EPI 3: +bias +resid -> f32.
// ---------------------------------------------------------------------------
template<int EPI>
__global__ __launch_bounds__(256, 2) void gemm_kernel(
    const short* __restrict__ A, const short* __restrict__ BT, void* outv,
    const float* __restrict__ bias, const float* __restrict__ resid,
    int N, int K)
{
    __shared__ short As[128][64];
    __shared__ short Bs[128][64];
    int bid = blockIdx.x;
    const int cpx = gridDim.x >> 3;
    bid = (bid & 7) * cpx + (bid >> 3);     // XCD swizzle (grid % 8 == 0)
    const int nb = N >> 7;
    const int m0 = (bid / nb) << 7;
    const int n0 = (bid % nb) << 7;
    const int t = threadIdx.x, l = t & 63, w = t >> 6;
    const int wm = w >> 1, wn = w & 1;
    const int lo = l & 15, hi = l >> 4;

    f32x4 acc[4][4] = {};
    const int srow = l >> 3;
    const int scg  = (l & 7) ^ (srow & 7);

    for (int kt = 0; kt < K; kt += 64) {
#pragma unroll
        for (int i = 0; i < 4; ++i) {
            int seg = w * 4 + i;
            int row = seg * 8 + srow;
            GLOAD_LDS16(A + (size_t)(m0 + row) * K + kt + scg * 8, &As[seg * 8][0]);
        }
#pragma unroll
        for (int i = 0; i < 4; ++i) {
            int seg = w * 4 + i;
            int row = seg * 8 + srow;
            GLOAD_LDS16(BT + (size_t)(n0 + row) * K + kt + scg * 8, &Bs[seg * 8][0]);
        }
        __syncthreads();
#pragma unroll
        for (int kk = 0; kk < 2; ++kk) {
            short8 af[4], bfv[4];
            const int rc = ((kk * 4 + hi) ^ (lo & 7)) * 8;
#pragma unroll
            for (int mi = 0; mi < 4; ++mi)
                af[mi] = *(const short8*)&As[wm * 64 + mi * 16 + lo][rc];
#pragma unroll
            for (int ni = 0; ni < 4; ++ni)
                bfv[ni] = *(const short8*)&Bs[wn * 64 + ni * 16 + lo][rc];
            __builtin_amdgcn_s_setprio(1);
#pragma unroll
            for (int mi = 0; mi < 4; ++mi)
#pragma unroll
                for (int ni = 0; ni < 4; ++ni)
                    acc[mi][ni] = __builtin_amdgcn_mfma_f32_16x16x32_bf16(
                        af[mi], bfv[ni], acc[mi][ni], 0, 0, 0);
            __builtin_amdgcn_s_setprio(0);
        }
        __syncthreads();
    }

#pragma unroll
    for (int mi = 0; mi < 4; ++mi) {
#pragma unroll
        for (int ni = 0; ni < 4; ++ni) {
#pragma unroll
            for (int r = 0; r < 4; ++r) {
                int row = m0 + wm * 64 + mi * 16 + hi * 4 + r;
                int col = n0 + wn * 64 + ni * 16 + lo;
                size_t idx = (size_t)row * N + col;
                float v = acc[mi][ni][r];
                if (EPI == 2) {
                    v += bias[col];
                    v = 0.5f * v * (1.0f + erff(v * 0.70710678118654752f));
                    ((short*)outv)[idx] = f2bf(v);
                } else {
                    v += bias[col] + resid[idx];
                    ((float*)outv)[idx] = v;
                }
            }
        }
    }
}

// ---------------------------------------------------------------------------
// Flash attention + residual + FUSED LayerNorm. Software-pipelined:
// QK/softmax(t+1) computed BEFORE PV(t); 1 barrier/tile; Ps/mpart double-
// buffered; carried alpha rescales o. grid 256, 8 waves, 64 q-rows/block.
// ---------------------------------------------------------------------------
__global__ __launch_bounds__(512, 2) void flash_kernel(
    const float* __restrict__ x,    // [8][2048][512] f32
    const short* __restrict__ qbf,  // frag-RC
    const short* __restrict__ kbff, // frag-RC
    const short* __restrict__ vbf,  // frag-CR
    float* __restrict__ xres,       // [8][2048][512] f32
    const float* __restrict__ gamma,
    const float* __restrict__ beta,
    short* __restrict__ hb)         // [16384][512] bf16 (LN output)
{
    __shared__ short Ps[2][2][8][512];   // [buf][qh][key16-blk][lane*8] 32 KB
    __shared__ float mpart[2][8][32];
    __shared__ float lpart[8][32];
    __shared__ float rsum[8][64];
    __shared__ float rsq[8][64];
    __shared__ float murs[2][64];

    const int bid = blockIdx.x;
    const int n = bid & 7;
    const int qtile = bid >> 3;          // 0..31
    const int q0 = qtile << 6;
    const int t = threadIdx.x, l = t & 63, w = t >> 6;
    const int qh = w >> 2, kq = w & 3;
    const int lo5 = l & 31, hi2 = l >> 5;
    const float C1 = 0.08838834764831845f * 1.4426950408889634f; // scale*log2e
    const float THR = 90.509668f;        // 8 nat units / scale

    // Q B-fragments for my q-half (32 q-rows)
    short8 qf[8];
    {
        const short* qp = qbf + (((size_t)(n * 64 + qtile * 2 + qh) * 8) << 9) + l * 8;
#pragma unroll
        for (int s = 0; s < 8; ++s) qf[s] = *(const short8*)(qp + (s << 9));
    }

    f32x16 o00 = {}, o01 = {}, o10 = {}, o11 = {};
    float m0 = -1e30f, m1 = -1e30f, lp = 0.f;
    float ac0 = 0.f, ac1 = 0.f;          // carried alpha (applied before PV(t))

    const short* kb0 = kbff + (((size_t)(n * 64) * 8) << 9);
    const short* vb0 = vbf + ((((size_t)(n * 128)) * 16 + w * 2) << 9);

    // ---- prologue: QK(0) + softmax(0) + pack -> Ps[0] ----
    {
        const short* kp = kb0 + (((size_t)kq * 8) << 9) + l * 8;
        short8 kf[8];
#pragma unroll
        for (int s = 0; s < 8; ++s) kf[s] = *(const short8*)(kp + (s << 9));
        f32x16 sa = {};
        __builtin_amdgcn_s_setprio(1);
#pragma unroll
        for (int s = 0; s < 8; ++s)
            sa = __builtin_amdgcn_mfma_f32_32x32x16_bf16(kf[s], qf[s], sa, 0, 0, 0);
        __builtin_amdgcn_s_setprio(0);
        float lmax = sa[0];
#pragma unroll
        for (int r = 1; r < 16; ++r) lmax = fmaxf(lmax, sa[r]);
        lmax = fmaxf(lmax, __shfl_xor(lmax, 32));
        if (l < 32) mpart[0][w][l] = lmax;
        __syncthreads();
        m0 = fmaxf(fmaxf(mpart[0][0][lo5], mpart[0][1][lo5]),
                   fmaxf(mpart[0][2][lo5], mpart[0][3][lo5]));
        m1 = fmaxf(fmaxf(mpart[0][4][lo5], mpart[0][5][lo5]),
                   fmaxf(mpart[0][6][lo5], mpart[0][7][lo5]));
        const float mC1 = (qh ? m1 : m0) * C1;
        float lsum = 0.f;
#pragma unroll
        for (int r = 0; r < 16; ++r) {
            float p = exp2f(fmaf(sa[r], C1, -mC1));
            sa[r] = p; lsum += p;
        }
        lp = lsum;
        // pack -> Ps[0]
        int wq[8], sx[8];
#pragma unroll
        for (int q2 = 0; q2 < 8; ++q2) {
            int a;
            asm("v_cvt_pk_bf16_f32 %0, %1, %2"
                : "=v"(a) : "v"(sa[2 * q2]), "v"(sa[2 * q2 + 1]));
            wq[q2] = a;
        }
#pragma unroll
        for (int q2 = 0; q2 < 8; ++q2) sx[q2] = __shfl_xor(wq[q2], 32);
        union { int i[4]; short8 v; } u0, u1;
        u0.i[0] = hi2 ? sx[2] : wq[0];
        u0.i[1] = hi2 ? sx[3] : wq[1];
        u0.i[2] = hi2 ? wq[2] : sx[0];
        u0.i[3] = hi2 ? wq[3] : sx[1];
        u1.i[0] = hi2 ? sx[6] : wq[4];
        u1.i[1] = hi2 ? sx[7] : wq[5];
        u1.i[2] = hi2 ? wq[6] : sx[4];
        u1.i[3] = hi2 ? wq[7] : sx[5];
        *(short8*)&Ps[0][qh][kq * 2][l * 8]     = u0.v;
        *(short8*)&Ps[0][qh][kq * 2 + 1][l * 8] = u1.v;
    }

    // ---- main loop: 16 tiles of 128 keys; QK/softmax(t+1) before PV(t) ----
    for (int kt2 = 0; kt2 < 16; ++kt2) {
        const bool hn = kt2 < 15;
        const short* vp = vb0 + (((size_t)(kt2 * 128)) << 9) + l * 8;

        // V first half (key-blocks 0..3 of this tile)
        short8 vfa[8];
#pragma unroll
        for (int p = 0; p < 8; ++p)
            vfa[p] = *(const short8*)(vp + (((size_t)((p >> 1) * 16 + (p & 1))) << 9));

        f32x16 sa;
        float an0 = 1.f, an1 = 1.f;
        if (hn) {
            const short* kp = kb0 + (((size_t)((kt2 + 1) * 4 + kq) * 8) << 9) + l * 8;
            short8 kf[8];
#pragma unroll
            for (int s = 0; s < 8; ++s) kf[s] = *(const short8*)(kp + (s << 9));
            f32x16 z = {};
            sa = z;
            __builtin_amdgcn_s_setprio(1);
#pragma unroll
            for (int s = 0; s < 8; ++s)
                sa = __builtin_amdgcn_mfma_f32_32x32x16_bf16(kf[s], qf[s], sa, 0, 0, 0);
            __builtin_amdgcn_s_setprio(0);
            float lmax = sa[0];
#pragma unroll
            for (int r = 1; r < 16; ++r) lmax = fmaxf(lmax, sa[r]);
            lmax = fmaxf(lmax, __shfl_xor(lmax, 32));
            if (l < 32) mpart[(kt2 + 1) & 1][w][l] = lmax;
        }
        __syncthreads();   // mpart(t+1) + Ps[t&1] pack-writes visible

        // V second half (key-blocks 4..7 of this tile)
        short8 vfb[8];
#pragma unroll
        for (int p = 0; p < 8; ++p)
            vfb[p] = *(const short8*)(vp + (((size_t)((4 + (p >> 1)) * 16 + (p & 1))) << 9));

        if (hn) {
            const int mb = (kt2 + 1) & 1;
            float nm0 = fmaxf(fmaxf(mpart[mb][0][lo5], mpart[mb][1][lo5]),
                              fmaxf(mpart[mb][2][lo5], mpart[mb][3][lo5]));
            float nm1 = fmaxf(fmaxf(mpart[mb][4][lo5], mpart[mb][5][lo5]),
                              fmaxf(mpart[mb][6][lo5], mpart[mb][7][lo5]));
            float t0 = (nm0 > m0 + THR) ? nm0 : m0;
            float t1 = (nm1 > m1 + THR) ? nm1 : m1;
            an0 = exp2f((m0 - t0) * C1);
            an1 = exp2f((m1 - t1) * C1);
            m0 = t0; m1 = t1;
            const float mC1 = (qh ? m1 : m0) * C1;
            float lsum = 0.f;
#pragma unroll
            for (int r = 0; r < 16; ++r) {
                float p = exp2f(fmaf(sa[r], C1, -mC1));
                sa[r] = p; lsum += p;
            }
            lp = lp * (qh ? an1 : an0) + lsum;
        }

        // rescale o with CARRIED alpha (rare: defer-max)
        if (!(__all(ac0 == 1.f) & __all(ac1 == 1.f))) {
#pragma unroll
            for (int r = 0; r < 16; ++r) {
                int qr = (r & 3) + 8 * (r >> 2) + 4 * hi2;
                float ar0 = __shfl(ac0, qr);
                float ar1 = __shfl(ac1, qr);
                o00[r] *= ar0; o01[r] *= ar0;
                o10[r] *= ar1; o11[r] *= ar1;
            }
        }

        // PV(t): Ps[t&1] x V
        const int pb = kt2 & 1;
        __builtin_amdgcn_s_setprio(1);
#pragma unroll
        for (int ks = 0; ks < 4; ++ks) {
            short8 p0 = *(const short8*)&Ps[pb][0][ks][l * 8];
            short8 p1 = *(const short8*)&Ps[pb][1][ks][l * 8];
            o00 = __builtin_amdgcn_mfma_f32_32x32x16_bf16(p0, vfa[ks * 2 + 0], o00, 0, 0, 0);
            o01 = __builtin_amdgcn_mfma_f32_32x32x16_bf16(p0, vfa[ks * 2 + 1], o01, 0, 0, 0);
            o10 = __builtin_amdgcn_mfma_f32_32x32x16_bf16(p1, vfa[ks * 2 + 0], o10, 0, 0, 0);
            o11 = __builtin_amdgcn_mfma_f32_32x32x16_bf16(p1, vfa[ks * 2 + 1], o11, 0, 0, 0);
        }
#pragma unroll
        for (int ks = 4; ks < 8; ++ks) {
            short8 p0 = *(const short8*)&Ps[pb][0][ks][l * 8];
            short8 p1 = *(const short8*)&Ps[pb][1][ks][l * 8];
            o00 = __builtin_amdgcn_mfma_f32_32x32x16_bf16(p0, vfb[(ks - 4) * 2 + 0], o00, 0, 0, 0);
            o01 = __builtin_amdgcn_mfma_f32_32x32x16_bf16(p0, vfb[(ks - 4) * 2 + 1], o01, 0, 0, 0);
            o10 = __builtin_amdgcn_mfma_f32_32x32x16_bf16(p1, vfb[(ks - 4) * 2 + 0], o10, 0, 0, 0);
            o11 = __builtin_amdgcn_mfma_f32_32x32x16_bf16(p1, vfb[(ks - 4) * 2 + 1], o11, 0, 0, 0);
        }
        __builtin_amdgcn_s_setprio(0);

        if (hn) {
            // pack(t+1) -> Ps[(t+1)&1]
            int wq[8], sx[8];
#pragma unroll
            for (int q2 = 0; q2 < 8; ++q2) {
                int a;
                asm("v_cvt_pk_bf16_f32 %0, %1, %2"
                    : "=v"(a) : "v"(sa[2 * q2]), "v"(sa[2 * q2 + 1]));
                wq[q2] = a;
            }
#pragma unroll
            for (int q2 = 0; q2 < 8; ++q2) sx[q2] = __shfl_xor(wq[q2], 32);
            union { int i[4]; short8 v; } u0, u1;
            u0.i[0] = hi2 ? sx[2] : wq[0];
            u0.i[1] = hi2 ? sx[3] : wq[1];
            u0.i[2] = hi2 ? wq[2] : sx[0];
            u0.i[3] = hi2 ? wq[3] : sx[1];
            u1.i[0] = hi2 ? sx[6] : wq[4];
            u1.i[1] = hi2 ? sx[7] : wq[5];
            u1.i[2] = hi2 ? wq[6] : sx[4];
            u1.i[3] = hi2 ? wq[7] : sx[5];
            const int nb2 = (kt2 + 1) & 1;
            *(short8*)&Ps[nb2][qh][kq * 2][l * 8]     = u0.v;
            *(short8*)&Ps[nb2][qh][kq * 2 + 1][l * 8] = u1.v;
            ac0 = an0; ac1 = an1;
        }
    }

    // ---- epilogue: l-merge, normalize, residual -> xres; fused LN -> hb ----
    float l2 = lp + __shfl_xor(lp, 32);
    if (l < 32) lpart[w][l] = l2;
    __syncthreads();
    float li0 = 1.f / (lpart[0][lo5] + lpart[1][lo5] + lpart[2][lo5] + lpart[3][lo5]);
    float li1 = 1.f / (lpart[4][lo5] + lpart[5][lo5] + lpart[6][lo5] + lpart[7][lo5]);
    const int c0 = w * 64 + lo5;
#pragma unroll
    for (int r = 0; r < 16; ++r) {
        int qr = (r & 3) + 8 * (r >> 2) + 4 * hi2;
        float ir0 = __shfl(li0, qr);
        float ir1 = __shfl(li1, qr);
        size_t b0 = ((size_t)(n * 2048 + q0 + qr) << 9) + c0;
        size_t b1 = ((size_t)(n * 2048 + q0 + 32 + qr) << 9) + c0;
        float v00 = x[b0]      + o00[r] * ir0;
        float v01 = x[b0 + 32] + o01[r] * ir0;
        float v10 = x[b1]      + o10[r] * ir1;
        float v11 = x[b1 + 32] + o11[r] * ir1;
        xres[b0] = v00; xres[b0 + 32] = v01;
        xres[b1] = v10; xres[b1 + 32] = v11;
        o00[r] = v00; o01[r] = v01; o10[r] = v10; o11[r] = v11;
        float s0 = v00 + v01, sq0 = v00 * v00 + v01 * v01;
        float s1 = v10 + v11, sq1 = v10 * v10 + v11 * v11;
#pragma unroll
        for (int mm = 1; mm < 32; mm <<= 1) {
            s0 += __shfl_xor(s0, mm); sq0 += __shfl_xor(sq0, mm);
            s1 += __shfl_xor(s1, mm); sq1 += __shfl_xor(sq1, mm);
        }
        if (lo5 == 0) {
            rsum[w][qr] = s0;      rsq[w][qr] = sq0;
            rsum[w][32 + qr] = s1; rsq[w][32 + qr] = sq1;
        }
    }
    __syncthreads();
    if (t < 64) {
        float s = 0.f, qq = 0.f;
#pragma unroll
        for (int ww = 0; ww < 8; ++ww) { s += rsum[ww][t]; qq += rsq[ww][t]; }
        float mu = s * (1.0f / 512.0f);
        float var = qq * (1.0f / 512.0f) - mu * mu;
        murs[0][t] = mu;
        murs[1][t] = rsqrtf(var + 1e-5f);
    }
    __syncthreads();
    const float g0 = gamma[c0], g1 = gamma[c0 + 32];
    const float e0 = beta[c0],  e1 = beta[c0 + 32];
#pragma unroll
    for (int r = 0; r < 16; ++r) {
        int qr = (r & 3) + 8 * (r >> 2) + 4 * hi2;
        float mu0 = murs[0][qr],      rs0 = murs[1][qr];
        float mu1 = murs[0][32 + qr], rs1 = murs[1][32 + qr];
        size_t h0 = ((size_t)(n * 2048 + q0 + qr) << 9) + c0;
        size_t h1 = ((size_t)(n * 2048 + q0 + 32 + qr) << 9) + c0;
        hb[h0]      = f2bf((o00[r] - mu0) * rs0 * g0 + e0);
        hb[h0 + 32] = f2bf((o01[r] - mu0) * rs0 * g1 + e1);
        hb[h1]      = f2bf((o10[r] - mu1) * rs1 * g0 + e0);
        hb[h1 + 32] = f2bf((o11[r] - mu1) * rs1 * g1 + e1);
    }
}

// ---------------------------------------------------------------------------
extern "C" void kernel_launch(void* const* d_in, const int* in_sizes, int n_in,
                              void* d_out, int out_size, void* d_ws, size_t ws_size,
                              hipStream_t stream)
{
    const float* x     = (const float*)d_in[0];
    const float* y     = (const float*)d_in[1];
    const float* Wq    = (const float*)d_in[2];
    const float* Wk    = (const float*)d_in[3];
    const float* Wv    = (const float*)d_in[4];
    const float* gamma = (const float*)d_in[5];
    const float* beta  = (const float*)d_in[6];
    const float* W1    = (const float*)d_in[7];
    const float* b1    = (const float*)d_in[8];
    const float* W2    = (const float*)d_in[9];
    const float* b2    = (const float*)d_in[10];
    float* out = (float*)d_out;

    char* ws = (char*)d_ws;
    size_t off = 0;
    auto alloc = [&](size_t bytes) -> void* {
        void* p = ws + off;
        off += (bytes + 255) & ~(size_t)255;
        return p;
    };
    short* WqT  = (short*)alloc((size_t)128 * 512 * 2);
    short* WkT  = (short*)alloc((size_t)128 * 512 * 2);
    short* WvT  = (short*)alloc((size_t)512 * 512 * 2);
    short* W1T  = (short*)alloc((size_t)1024 * 512 * 2);
    short* W2T  = (short*)alloc((size_t)512 * 1024 * 2);
    short* qbf  = (short*)alloc((size_t)16384 * 128 * 2);   // frag-RC
    short* kbff = (short*)alloc((size_t)16384 * 128 * 2);   // frag-RC
    short* vbf  = (short*)alloc((size_t)16384 * 512 * 2);   // frag-CR
    short* xb   = (short*)alloc((size_t)16384 * 512 * 2);   // later: hb
    short* hb   = xb;
    short* yb   = (short*)alloc((size_t)16384 * 512 * 2);
    short* gb   = (short*)alloc((size_t)16384 * 1024 * 2);

    // 1. prep: x,y -> bf16 + weight transposes
    prep_kernel<<<8544, 256, 0, stream>>>(x, y, Wq, Wk, Wv, W1, W2,
                                          xb, yb, WqT, WkT, WvT, W1T, W2T);
    // 2. fused q/k/v projections -> fragment-major layouts
    proj_gemm<<<768, 256, 0, stream>>>(xb, yb, WqT, WkT, WvT, qbf, kbff, vbf);
    // 3. attention + residual + fused LN -> xres(d_out), hb
    flash_kernel<<<256, 512, 0, stream>>>(x, qbf, kbff, vbf, out, gamma, beta, hb);
    // 4. MLP
    gemm_kernel<2><<<1024, 256, 0, stream>>>(hb, W1T, gb, b1, nullptr, 1024, 512);
    gemm_kernel<3><<<512,  256, 0, stream>>>(gb, W2T, out, b2, out, 512, 1024);

    (void)in_sizes; (void)n_in; (void)out_size; (void)ws_size;
}